// Round 2
// baseline (1240.352 us; speedup 1.0000x reference)
//
#include <hip/hip_runtime.h>
#include <hip/hip_bf16.h>
#include <math.h>

#define BATCH 64
#define CIN   1024
#define HH    14
#define WW    14
#define P     196      // HH*WW
#define NHEAD 8
#define DKH   64
#define DKTOT 512

// ws layout (floats)
#define OFF_Y    0
#define N_Y      (BATCH*1024*P)
#define OFF_INK  (OFF_Y + N_Y)
#define N_INK    (BATCH*NHEAD*P)
#define OFF_SQ   (OFF_INK + N_INK)
#define N_SQ     (BATCH*NHEAD*DKH)
#define OFF_QH   (OFF_SQ + N_SQ)
#define N_QH     (BATCH*HH*DKH)
#define OFF_QW   (OFF_QH + N_QH)
#define N_QW     (BATCH*WW*DKH)
#define OFF_ATTN (OFF_QW + N_QW)

// ---------------- Kernel 1: qk GEMM  Y[b,o,p] = bias[o] + sum_c W[o,c]*x[b,c,p], o<1024
__global__ __launch_bounds__(256) void k_qkgemm(const float* __restrict__ x,
                                                const float* __restrict__ Wq,
                                                const float* __restrict__ bias,
                                                float* __restrict__ Y) {
    const int ot = blockIdx.x;          // 0..31  (32 rows each)
    const int b  = blockIdx.y;
    const int o0 = ot * 32;
    const int tid = threadIdx.x;
    const int p  = tid;
    const int pc = (p < P) ? p : 0;
    __shared__ float xs[16][P];
    float acc[32];
#pragma unroll
    for (int r = 0; r < 32; ++r) acc[r] = 0.f;
    const float* xb = x + (size_t)b * (CIN * P);
    for (int c0 = 0; c0 < CIN; c0 += 16) {
        for (int idx = tid; idx < 16 * P; idx += 256) {
            int cc = idx / P, pp = idx - cc * P;
            xs[cc][pp] = xb[(c0 + cc) * P + pp];
        }
        __syncthreads();
        const float* wp = Wq + (size_t)o0 * CIN + c0;   // block-uniform -> s_load
#pragma unroll
        for (int cc = 0; cc < 16; ++cc) {
            float xv = xs[cc][pc];
#pragma unroll
            for (int r = 0; r < 32; ++r)
                acc[r] = fmaf(wp[r * CIN + cc], xv, acc[r]);
        }
        __syncthreads();
    }
    if (p < P) {
#pragma unroll
        for (int r = 0; r < 32; ++r)
            Y[(size_t)b * (1024 * P) + (o0 + r) * P + p] = acc[r] + bias[o0 + r];
    }
}

// ---------------- Kernel 2a: per-(b,n) k-norms (store 1/||k||) and Sq[b,n,d] = sum_p qn
__global__ __launch_bounds__(256) void k_norm(const float* __restrict__ Y,
                                              float* __restrict__ ink_g,
                                              float* __restrict__ sq_g) {
    const int bn = blockIdx.x;          // b*8+n
    const int b = bn >> 3, n = bn & 7;
    const int tid = threadIdx.x;
    const int p = tid;
    const bool act = (p < P);
    const int pc = act ? p : 0;
    const float* Yq = Y + (size_t)b * (1024 * P) + (n * DKH) * P;
    const float* Yk = Y + (size_t)b * (1024 * P) + (DKTOT + n * DKH) * P;
    float sq = 0.f, sk = 0.f;
    for (int d = 0; d < DKH; ++d) {
        float qv = Yq[d * P + pc];
        float kv = Yk[d * P + pc];
        sq = fmaf(qv, qv, sq);
        sk = fmaf(kv, kv, sk);
    }
    float inq = rsqrtf(sq);
    float ink = rsqrtf(sk);
    if (act) ink_g[bn * P + p] = ink;
    __shared__ float Sq_s[DKH];
    if (tid < DKH) Sq_s[tid] = 0.f;
    __syncthreads();
    const int lane = tid & 63;
    for (int d = 0; d < DKH; ++d) {
        float v = act ? Yq[d * P + p] * inq : 0.f;
#pragma unroll
        for (int off = 32; off >= 1; off >>= 1)
            v += __shfl_xor(v, off, 64);
        if (lane == 0) atomicAdd(&Sq_s[d], v);
    }
    __syncthreads();
    if (tid < DKH) sq_g[bn * DKH + tid] = Sq_s[tid];
}

// ---------------- Kernel 2b: per-b qsum_h[x,d] = sum_{n,y} q/8 ; qsum_w[y,d] = sum_{n,x} q/8
__global__ __launch_bounds__(256) void k_qsum(const float* __restrict__ Y,
                                              float* __restrict__ qh_g,
                                              float* __restrict__ qw_g) {
    const int b = blockIdx.x;
    const int tid = threadIdx.x;
    __shared__ float qh[HH][DKH];
    __shared__ float qw[WW][DKH];
    for (int i = tid; i < HH * DKH; i += 256) { (&qh[0][0])[i] = 0.f; (&qw[0][0])[i] = 0.f; }
    __syncthreads();
    for (int id = tid; id < NHEAD * DKH; id += 256) {
        int n = id >> 6, d = id & 63;
        const float* Yq = Y + (size_t)b * (1024 * P) + (n * DKH + d) * P;
        float rs[HH], cs[WW];
#pragma unroll
        for (int i = 0; i < HH; ++i) { rs[i] = 0.f; cs[i] = 0.f; }
        for (int xr = 0; xr < HH; ++xr) {
#pragma unroll
            for (int yc = 0; yc < WW; ++yc) {
                float v = Yq[xr * WW + yc];
                rs[xr] += v; cs[yc] += v;
            }
        }
#pragma unroll
        for (int i = 0; i < HH; ++i) atomicAdd(&qh[i][d], rs[i] * 0.125f);
#pragma unroll
        for (int i = 0; i < WW; ++i) atomicAdd(&qw[i][d], cs[i] * 0.125f);
    }
    __syncthreads();
    for (int i = tid; i < HH * DKH; i += 256) {
        qh_g[b * HH * DKH + i] = (&qh[0][0])[i];
        qw_g[b * WW * DKH + i] = (&qw[0][0])[i];
    }
}

// ---------------- Kernel 4a: per-b Savg, A_w, A_h, dot-part, mean_logits, softmax -> attn
__global__ __launch_bounds__(256) void k_attn(const float* __restrict__ Y,
                                              const float* __restrict__ ink_g,
                                              const float* __restrict__ sq_g,
                                              const float* __restrict__ qh_g,
                                              const float* __restrict__ qw_g,
                                              const float* __restrict__ relw,
                                              const float* __restrict__ relh,
                                              const int*   __restrict__ pair,
                                              float* __restrict__ attn_g) {
    const int b = blockIdx.x;
    const int tid = threadIdx.x;
    __shared__ float Sav[NHEAD * DKH];
    __shared__ float Aw[WW], Ah[HH];
    __shared__ float red[256];
    const int pb = pair[b];
    for (int i = tid; i < NHEAD * DKH; i += 256)
        Sav[i] = 0.5f * (sq_g[b * NHEAD * DKH + i] + sq_g[pb * NHEAD * DKH + i]);
    if (tid < WW) {                      // A_w[Y]
        float s = 0.f;
        for (int y = 0; y < WW; ++y)
            for (int d = 0; d < DKH; ++d)
                s += qw_g[(b * WW + y) * DKH + d] * relw[(13 + tid - y) * DKH + d];
        Aw[tid] = s;
    } else if (tid >= 32 && tid < 32 + HH) {   // A_h[X]
        int X = tid - 32;
        float s = 0.f;
        for (int xr = 0; xr < HH; ++xr)
            for (int d = 0; d < DKH; ++d)
                s += qh_g[(b * HH + xr) * DKH + d] * relh[(13 + X - xr) * DKH + d];
        Ah[X] = s;
    }
    __syncthreads();
    const int p = tid;
    float ml = -1e30f;
    if (p < P) {
        float dot = 0.f;
        const float* Ykb = Y + (size_t)b * (1024 * P) + DKTOT * P;
        for (int n = 0; n < NHEAD; ++n) {
            float partial = 0.f;
#pragma unroll 8
            for (int d = 0; d < DKH; ++d)
                partial = fmaf(Sav[n * DKH + d], Ykb[(n * DKH + d) * P + p], partial);
            dot = fmaf(partial, ink_g[(b * NHEAD + n) * P + p], dot);
        }
        ml = (dot + Ah[p / WW] + Aw[p % WW]) * (1.0f / 1568.0f);
    }
    red[tid] = ml; __syncthreads();
    for (int s = 128; s > 0; s >>= 1) {
        if (tid < s) red[tid] = fmaxf(red[tid], red[tid + s]);
        __syncthreads();
    }
    float mx = red[0]; __syncthreads();
    float e = (p < P) ? expf(ml - mx) : 0.f;
    red[tid] = e; __syncthreads();
    for (int s = 128; s > 0; s >>= 1) {
        if (tid < s) red[tid] += red[tid + s];
        __syncthreads();
    }
    float sum = red[0];
    if (p < P) attn_g[b * P + p] = e / sum;
}

// ---------------- Kernel 4b: out = concat(x/49, x*attn) over channels
__global__ __launch_bounds__(256) void k_out(const float* __restrict__ x,
                                             const float* __restrict__ attn_g,
                                             float* __restrict__ out) {
    const int total4 = BATCH * CIN * P / 4;   // 3,211,264
    const int stride = gridDim.x * 256;
    const float4* x4 = (const float4*)x;
    const float4* a4 = (const float4*)attn_g;
    float4* o4 = (float4*)out;
    for (int i4 = blockIdx.x * 256 + threadIdx.x; i4 < total4; i4 += stride) {
        int i = i4 * 4;
        int b = i / (CIN * P);
        int r = i - b * (CIN * P);
        int p0 = r % P;                    // P%4==0 -> p0..p0+3 same row
        float4 xv = x4[i4];
        float4 at = a4[(b * P + p0) >> 2];
        float4 o1 = make_float4(xv.x * (1.f/49.f), xv.y * (1.f/49.f),
                                xv.z * (1.f/49.f), xv.w * (1.f/49.f));
        float4 o2 = make_float4(xv.x * at.x, xv.y * at.y, xv.z * at.z, xv.w * at.w);
        o4[(b * (2 * CIN * P) + r) >> 2] = o1;
        o4[(b * (2 * CIN * P) + CIN * P + r) >> 2] = o2;
    }
}

extern "C" void kernel_launch(void* const* d_in, const int* in_sizes, int n_in,
                              void* d_out, int out_size, void* d_ws, size_t ws_size,
                              hipStream_t stream) {
    const float* x    = (const float*)d_in[0];
    const float* Wq   = (const float*)d_in[1];
    const float* bias = (const float*)d_in[2];
    const float* relw = (const float*)d_in[3];
    const float* relh = (const float*)d_in[4];
    const int*   pair = (const int*)d_in[5];
    float* out = (float*)d_out;
    float* ws  = (float*)d_ws;

    float* Y    = ws + OFF_Y;
    float* ink  = ws + OFF_INK;
    float* sq   = ws + OFF_SQ;
    float* qh   = ws + OFF_QH;
    float* qw   = ws + OFF_QW;
    float* attn = ws + OFF_ATTN;

    k_qkgemm<<<dim3(32, 64), 256, 0, stream>>>(x, Wq, bias, Y);
    k_norm <<<BATCH * NHEAD, 256, 0, stream>>>(Y, ink, sq);
    k_qsum <<<BATCH, 256, 0, stream>>>(Y, qh, qw);
    k_attn <<<BATCH, 256, 0, stream>>>(Y, ink, sq, qh, qw, relw, relh, pair, attn);
    k_out  <<<2048, 256, 0, stream>>>(x, attn, out);
}

// Round 3
// 255.846 us; speedup vs baseline: 4.8480x; 4.8480x over previous
//
#include <hip/hip_runtime.h>
#include <hip/hip_bf16.h>
#include <math.h>

typedef unsigned short ushort_t;
using bf16x8 = __attribute__((ext_vector_type(8))) short;
using f32x4  = __attribute__((ext_vector_type(4))) float;

#define BATCH 64
#define CIN   1024
#define HH    14
#define WW    14
#define P     196
#define NHEAD 8
#define DKH   64
#define DKTOT 512
#define PPAD  224      // padded p rows for Xb

// ws layout (float indices)
#define OFF_Y    0
#define N_Y      (BATCH*1024*P)                 // 12,845,056
#define OFF_XB   (OFF_Y + N_Y)                  // ushort region
#define N_XB_F   (BATCH*PPAD*CIN/2)             // 7,340,032 floats
#define OFF_WB   (OFF_XB + N_XB_F)
#define N_WB_F   (1024*CIN/2)                   // 524,288 floats
#define OFF_INK  (OFF_WB + N_WB_F)
#define N_INK    (BATCH*NHEAD*P)
#define OFF_SQ   (OFF_INK + N_INK)
#define N_SQ     (BATCH*NHEAD*DKH)
#define OFF_QH   (OFF_SQ + N_SQ)
#define N_QH     (BATCH*HH*DKH)
#define OFF_QW   (OFF_QH + N_QH)
#define N_QW     (BATCH*WW*DKH)
#define OFF_ATTN (OFF_QW + N_QW)

__device__ __forceinline__ ushort_t f2bf(float f) {
    union { float f; unsigned u; } v; v.f = f;
    unsigned r = v.u + 0x7fffu + ((v.u >> 16) & 1u);   // RNE
    return (ushort_t)(r >> 16);
}

// ---------------- W -> bf16 [o][c], k-contiguous
__global__ __launch_bounds__(256) void k_convW(const float* __restrict__ Wq,
                                               ushort_t* __restrict__ Wb) {
    int i = blockIdx.x * 256 + threadIdx.x;      // 4 floats each
    const float4 v = ((const float4*)Wq)[i];
    ushort4 o;
    o.x = f2bf(v.x); o.y = f2bf(v.y); o.z = f2bf(v.z); o.w = f2bf(v.w);
    ((ushort4*)Wb)[i] = o;
}

// ---------------- x -> bf16 transposed Xb[b][p][c], p padded to 224 (zeros)
__global__ __launch_bounds__(256) void k_trans(const float* __restrict__ x,
                                               ushort_t* __restrict__ Xb) {
    const int c0 = blockIdx.x * 64, p0 = blockIdx.y * 32, b = blockIdx.z;
    const int t = threadIdx.x;
    __shared__ float tile[64][33];
    const float* xb = x + (size_t)b * (CIN * P);
#pragma unroll
    for (int it = 0; it < 8; ++it) {
        int idx = t + it * 256;                 // [64c x 32p]
        int c_l = idx >> 5, p_l = idx & 31;
        int p = p0 + p_l;
        tile[c_l][p_l] = (p < P) ? xb[(size_t)(c0 + c_l) * P + p] : 0.f;
    }
    __syncthreads();
    int c_chunk = (t & 7) * 8, p_l = t >> 3;    // 8 chunks x 32 rows
    ushort_t buf[8];
#pragma unroll
    for (int e = 0; e < 8; ++e) buf[e] = f2bf(tile[c_chunk + e][p_l]);
    *(uint4*)(Xb + ((size_t)b * PPAD + p0 + p_l) * CIN + c0 + c_chunk) = *(uint4*)buf;
}

// ---------------- MFMA GEMM: Y[b,o,p] = bias[o] + sum_c Wb[o,c]*Xb[b,p,c]
// block: 112 p x 256 o, 4 waves (each wave: all 7 m-frags x 4 o-tiles), BK=64
#define LDP 72   // LDS row pitch in bf16 (144B -> 2-way max conflict, free)
__global__ __launch_bounds__(256, 2) void k_mfma(const ushort_t* __restrict__ Xb,
                                                 const ushort_t* __restrict__ Wb,
                                                 const float* __restrict__ bias,
                                                 float* __restrict__ Y) {
    const int nb = blockIdx.x, mb = blockIdx.y, b = blockIdx.z;
    const int o0 = nb * 256, m0 = mb * 112;
    const int tid = threadIdx.x, w = tid >> 6, l = tid & 63;
    __shared__ ushort_t xa[112 * LDP];
    __shared__ ushort_t xw[256 * LDP];
    f32x4 acc[7][4];
#pragma unroll
    for (int mf = 0; mf < 7; ++mf)
#pragma unroll
        for (int j = 0; j < 4; ++j) acc[mf][j] = (f32x4){0.f, 0.f, 0.f, 0.f};

    const ushort_t* Xrow = Xb + (size_t)b * PPAD * CIN + (size_t)m0 * CIN;
    const ushort_t* Wrow = Wb + (size_t)o0 * CIN;

    for (int c0 = 0; c0 < CIN; c0 += 64) {
        __syncthreads();
        // stage A tile: 112 rows x 64 c  (896 x 8-bf16 chunks)
        for (int i = tid; i < 896; i += 256) {
            int row = i >> 3, kc = (i & 7) * 8;
            uint4 v = *(const uint4*)(Xrow + (size_t)row * CIN + c0 + kc);
            *(uint4*)(xa + row * LDP + kc) = v;
        }
        // stage B tile: 256 rows x 64 c  (2048 chunks)
        for (int i = tid; i < 2048; i += 256) {
            int row = i >> 3, kc = (i & 7) * 8;
            uint4 v = *(const uint4*)(Wrow + (size_t)row * CIN + c0 + kc);
            *(uint4*)(xw + row * LDP + kc) = v;
        }
        __syncthreads();
#pragma unroll
        for (int kk = 0; kk < 2; ++kk) {
            bf16x8 bfrag[4];
#pragma unroll
            for (int j = 0; j < 4; ++j)
                bfrag[j] = *(const bf16x8*)(xw + (w * 64 + j * 16 + (l & 15)) * LDP + kk * 32 + (l >> 4) * 8);
#pragma unroll
            for (int mf = 0; mf < 7; ++mf) {
                bf16x8 afrag = *(const bf16x8*)(xa + (mf * 16 + (l & 15)) * LDP + kk * 32 + (l >> 4) * 8);
#pragma unroll
                for (int j = 0; j < 4; ++j)
                    acc[mf][j] = __builtin_amdgcn_mfma_f32_16x16x32_bf16(afrag, bfrag[j], acc[mf][j], 0, 0, 0);
            }
        }
    }
    // epilogue: D[m=p][n=o]; lane l reg r -> p = m0+mf*16+(l>>4)*4+r, o = o0+w*64+j*16+(l&15)
    float* Yb = Y + (size_t)b * (1024 * P);
    const int pq = (l >> 4) * 4, oc = l & 15;
#pragma unroll
    for (int j = 0; j < 4; ++j) {
        int o = o0 + w * 64 + j * 16 + oc;
        float bo = bias[o];
#pragma unroll
        for (int mf = 0; mf < 7; ++mf) {
            int p = m0 + mf * 16 + pq;
            if (p + 3 < P) {
                float4 v = make_float4(acc[mf][j][0] + bo, acc[mf][j][1] + bo,
                                       acc[mf][j][2] + bo, acc[mf][j][3] + bo);
                *(float4*)(Yb + (size_t)o * P + p) = v;
            } else {
#pragma unroll
                for (int r = 0; r < 4; ++r)
                    if (p + r < P) Yb[(size_t)o * P + p + r] = acc[mf][j][r] + bo;
            }
        }
    }
}

// ---------------- per-(b,n) k-norms and Sq[b,n,d]
__global__ __launch_bounds__(256) void k_norm(const float* __restrict__ Y,
                                              float* __restrict__ ink_g,
                                              float* __restrict__ sq_g) {
    const int bn = blockIdx.x;
    const int b = bn >> 3, n = bn & 7;
    const int tid = threadIdx.x;
    const int p = tid;
    const bool act = (p < P);
    const int pc = act ? p : 0;
    const float* Yq = Y + (size_t)b * (1024 * P) + (n * DKH) * P;
    const float* Yk = Y + (size_t)b * (1024 * P) + (DKTOT + n * DKH) * P;
    float sq = 0.f, sk = 0.f;
    for (int d = 0; d < DKH; ++d) {
        float qv = Yq[d * P + pc];
        float kv = Yk[d * P + pc];
        sq = fmaf(qv, qv, sq);
        sk = fmaf(kv, kv, sk);
    }
    float inq = rsqrtf(sq);
    float ink = rsqrtf(sk);
    if (act) ink_g[bn * P + p] = ink;
    __shared__ float Sq_s[DKH];
    if (tid < DKH) Sq_s[tid] = 0.f;
    __syncthreads();
    const int lane = tid & 63;
    for (int d = 0; d < DKH; ++d) {
        float v = act ? Yq[d * P + p] * inq : 0.f;
#pragma unroll
        for (int off = 32; off >= 1; off >>= 1)
            v += __shfl_xor(v, off, 64);
        if (lane == 0) atomicAdd(&Sq_s[d], v);
    }
    __syncthreads();
    if (tid < DKH) sq_g[bn * DKH + tid] = Sq_s[tid];
}

// ---------------- per-b qsum_h / qsum_w
__global__ __launch_bounds__(256) void k_qsum(const float* __restrict__ Y,
                                              float* __restrict__ qh_g,
                                              float* __restrict__ qw_g) {
    const int b = blockIdx.x;
    const int tid = threadIdx.x;
    __shared__ float qh[HH][DKH];
    __shared__ float qw[WW][DKH];
    for (int i = tid; i < HH * DKH; i += 256) { (&qh[0][0])[i] = 0.f; (&qw[0][0])[i] = 0.f; }
    __syncthreads();
    for (int id = tid; id < NHEAD * DKH; id += 256) {
        int n = id >> 6, d = id & 63;
        const float* Yq = Y + (size_t)b * (1024 * P) + (n * DKH + d) * P;
        float rs[HH], cs[WW];
#pragma unroll
        for (int i = 0; i < HH; ++i) { rs[i] = 0.f; cs[i] = 0.f; }
        for (int xr = 0; xr < HH; ++xr) {
#pragma unroll
            for (int yc = 0; yc < WW; ++yc) {
                float v = Yq[xr * WW + yc];
                rs[xr] += v; cs[yc] += v;
            }
        }
#pragma unroll
        for (int i = 0; i < HH; ++i) atomicAdd(&qh[i][d], rs[i] * 0.125f);
#pragma unroll
        for (int i = 0; i < WW; ++i) atomicAdd(&qw[i][d], cs[i] * 0.125f);
    }
    __syncthreads();
    for (int i = tid; i < HH * DKH; i += 256) {
        qh_g[b * HH * DKH + i] = (&qh[0][0])[i];
        qw_g[b * WW * DKH + i] = (&qw[0][0])[i];
    }
}

// ---------------- per-b attn
__global__ __launch_bounds__(256) void k_attn(const float* __restrict__ Y,
                                              const float* __restrict__ ink_g,
                                              const float* __restrict__ sq_g,
                                              const float* __restrict__ qh_g,
                                              const float* __restrict__ qw_g,
                                              const float* __restrict__ relw,
                                              const float* __restrict__ relh,
                                              const int*   __restrict__ pair,
                                              float* __restrict__ attn_g) {
    const int b = blockIdx.x;
    const int tid = threadIdx.x;
    __shared__ float Sav[NHEAD * DKH];
    __shared__ float Aw[WW], Ah[HH];
    __shared__ float red[256];
    const int pb = pair[b];
    for (int i = tid; i < NHEAD * DKH; i += 256)
        Sav[i] = 0.5f * (sq_g[b * NHEAD * DKH + i] + sq_g[pb * NHEAD * DKH + i]);
    if (tid < WW) {
        float s = 0.f;
        for (int y = 0; y < WW; ++y)
            for (int d = 0; d < DKH; ++d)
                s += qw_g[(b * WW + y) * DKH + d] * relw[(13 + tid - y) * DKH + d];
        Aw[tid] = s;
    } else if (tid >= 32 && tid < 32 + HH) {
        int X = tid - 32;
        float s = 0.f;
        for (int xr = 0; xr < HH; ++xr)
            for (int d = 0; d < DKH; ++d)
                s += qh_g[(b * HH + xr) * DKH + d] * relh[(13 + X - xr) * DKH + d];
        Ah[X] = s;
    }
    __syncthreads();
    const int p = tid;
    float ml = -1e30f;
    if (p < P) {
        float dot = 0.f;
        const float* Ykb = Y + (size_t)b * (1024 * P) + DKTOT * P;
        for (int n = 0; n < NHEAD; ++n) {
            float partial = 0.f;
#pragma unroll 8
            for (int d = 0; d < DKH; ++d)
                partial = fmaf(Sav[n * DKH + d], Ykb[(n * DKH + d) * P + p], partial);
            dot = fmaf(partial, ink_g[(b * NHEAD + n) * P + p], dot);
        }
        ml = (dot + Ah[p / WW] + Aw[p % WW]) * (1.0f / 1568.0f);
    }
    red[tid] = ml; __syncthreads();
    for (int s = 128; s > 0; s >>= 1) {
        if (tid < s) red[tid] = fmaxf(red[tid], red[tid + s]);
        __syncthreads();
    }
    float mx = red[0]; __syncthreads();
    float e = (p < P) ? expf(ml - mx) : 0.f;
    red[tid] = e; __syncthreads();
    for (int s = 128; s > 0; s >>= 1) {
        if (tid < s) red[tid] += red[tid + s];
        __syncthreads();
    }
    float sum = red[0];
    if (p < P) attn_g[b * P + p] = e / sum;
}

// ---------------- out = concat(x/49, x*attn)
__global__ __launch_bounds__(256) void k_out(const float* __restrict__ x,
                                             const float* __restrict__ attn_g,
                                             float* __restrict__ out) {
    const int total4 = BATCH * CIN * P / 4;
    const int stride = gridDim.x * 256;
    const float4* x4 = (const float4*)x;
    const float4* a4 = (const float4*)attn_g;
    float4* o4 = (float4*)out;
    for (int i4 = blockIdx.x * 256 + threadIdx.x; i4 < total4; i4 += stride) {
        int i = i4 * 4;
        int b = i / (CIN * P);
        int r = i - b * (CIN * P);
        int p0 = r % P;
        float4 xv = x4[i4];
        float4 at = a4[(b * P + p0) >> 2];
        float4 o1 = make_float4(xv.x * (1.f/49.f), xv.y * (1.f/49.f),
                                xv.z * (1.f/49.f), xv.w * (1.f/49.f));
        float4 o2 = make_float4(xv.x * at.x, xv.y * at.y, xv.z * at.z, xv.w * at.w);
        o4[(b * (2 * CIN * P) + r) >> 2] = o1;
        o4[(b * (2 * CIN * P) + CIN * P + r) >> 2] = o2;
    }
}

extern "C" void kernel_launch(void* const* d_in, const int* in_sizes, int n_in,
                              void* d_out, int out_size, void* d_ws, size_t ws_size,
                              hipStream_t stream) {
    const float* x    = (const float*)d_in[0];
    const float* Wq   = (const float*)d_in[1];
    const float* bias = (const float*)d_in[2];
    const float* relw = (const float*)d_in[3];
    const float* relh = (const float*)d_in[4];
    const int*   pair = (const int*)d_in[5];
    float* out = (float*)d_out;
    float* ws  = (float*)d_ws;

    float*    Y    = ws + OFF_Y;
    ushort_t* Xb   = (ushort_t*)(ws + OFF_XB);
    ushort_t* Wb   = (ushort_t*)(ws + OFF_WB);
    float*    ink  = ws + OFF_INK;
    float*    sq   = ws + OFF_SQ;
    float*    qh   = ws + OFF_QH;
    float*    qw   = ws + OFF_QW;
    float*    attn = ws + OFF_ATTN;

    k_convW<<<1024, 256, 0, stream>>>(Wq, Wb);
    k_trans<<<dim3(16, 7, 64), 256, 0, stream>>>(x, Xb);
    k_mfma <<<dim3(4, 2, 64), 256, 0, stream>>>(Xb, Wb, bias, Y);
    k_norm <<<BATCH * NHEAD, 256, 0, stream>>>(Y, ink, sq);
    k_qsum <<<BATCH, 256, 0, stream>>>(Y, qh, qw);
    k_attn <<<BATCH, 256, 0, stream>>>(Y, ink, sq, qh, qw, relw, relh, pair, attn);
    k_out  <<<2048, 256, 0, stream>>>(x, attn, out);
}

// Round 5
// 129.380 us; speedup vs baseline: 9.5869x; 1.9775x over previous
//
#include <hip/hip_runtime.h>
#include <hip/hip_bf16.h>
#include <math.h>

typedef unsigned short ushort_t;
using bf16x8 = __attribute__((ext_vector_type(8))) short;
using f32x4  = __attribute__((ext_vector_type(4))) float;

#define BATCH 64
#define CIN   1024
#define HH    14
#define WW    14
#define P     196
#define NHEAD 8
#define DKH   64
#define PPAD  224      // padded p rows per batch; M_total = 64*224 = 14336

// ws layout (float indices)
#define OFF_Y16  0
#define N_Y16_F  6422528            // 64*1024*196 ushorts
#define OFF_XB   (OFF_Y16 + N_Y16_F)
#define N_XB_F   7340032            // 64*224*1024 ushorts
#define OFF_WB   (OFF_XB + N_XB_F)
#define N_WB_F   524288             // 1024*1024 ushorts
#define OFF_INK  (OFF_WB + N_WB_F)
#define N_INK    (BATCH*NHEAD*P)    // 100352
#define OFF_SQ   (OFF_INK + N_INK)
#define N_SQ     (BATCH*NHEAD*DKH)  // 32768
#define OFF_QH   (OFF_SQ + N_SQ)
#define N_QH     (BATCH*HH*DKH)     // 57344
#define OFF_QW   (OFF_QH + N_QH)
#define N_QW     (BATCH*WW*DKH)     // 57344
#define OFF_AW   (OFF_QW + N_QW)
#define N_AW     (BATCH*WW)         // 896
#define OFF_AH   (OFF_AW + N_AW)
#define N_AH     (BATCH*HH)         // 896
#define OFF_ML   (OFF_AH + N_AH)
#define N_ML     (BATCH*P)          // 12544
#define OFF_ATTN (OFF_ML + N_ML)
#define N_ATTN   (BATCH*P)
// zeroed region: [OFF_QH, OFF_ATTN) = 57344*2 + 896*2 + 12544 = 129024 floats
#define ZERO_FLOATS 129024

__device__ __forceinline__ ushort_t f2bf(float f) {
    union { float f; unsigned u; } v; v.f = f;
    unsigned r = v.u + 0x7fffu + ((v.u >> 16) & 1u);   // RNE
    return (ushort_t)(r >> 16);
}
__device__ __forceinline__ float bf2f(ushort_t u) {
    union { unsigned u; float f; } v; v.u = ((unsigned)u) << 16; return v.f;
}
__device__ __forceinline__ void gll16(const ushort_t* g, ushort_t* l) {
    __builtin_amdgcn_global_load_lds(
        (const __attribute__((address_space(1))) void*)g,
        (__attribute__((address_space(3))) void*)l, 16, 0, 0);
}

// ---------------- W -> bf16 [o][c] (linear, k-contiguous)
__global__ __launch_bounds__(256) void k_convW(const float* __restrict__ Wq,
                                               ushort_t* __restrict__ Wb) {
    int i = blockIdx.x * 256 + threadIdx.x;
    const float4 v = ((const float4*)Wq)[i];
    ushort4 o;
    o.x = f2bf(v.x); o.y = f2bf(v.y); o.z = f2bf(v.z); o.w = f2bf(v.w);
    ((ushort4*)Wb)[i] = o;
}

// ---------------- x -> bf16 transposed Xb[b][p][c], p padded to 224 (zeros)
__global__ __launch_bounds__(256) void k_trans(const float* __restrict__ x,
                                               ushort_t* __restrict__ Xb) {
    const int c0 = blockIdx.x * 64, p0 = blockIdx.y * 32, b = blockIdx.z;
    const int t = threadIdx.x;
    __shared__ float tile[64][33];
    const float* xb = x + (size_t)b * (CIN * P);
#pragma unroll
    for (int it = 0; it < 8; ++it) {
        int idx = t + it * 256;
        int c_l = idx >> 5, p_l = idx & 31;
        int p = p0 + p_l;
        tile[c_l][p_l] = (p < P) ? xb[(size_t)(c0 + c_l) * P + p] : 0.f;
    }
    __syncthreads();
    int c_chunk = (t & 7) * 8, p_l = t >> 3;
    ushort_t buf[8];
#pragma unroll
    for (int e = 0; e < 8; ++e) buf[e] = f2bf(tile[c_chunk + e][p_l]);
    *(uint4*)(Xb + ((size_t)b * PPAD + p0 + p_l) * CIN + c0 + c_chunk) = *(uint4*)buf;
}

// ---------------- MFMA GEMM (m97 structure): C[r,o] = bias[o] + sum_c Xb[r,c]*Wb[o,c]
// flat rows r=b*224+p, M=14336; 128x128 tile, BK=64, 4 waves (2x2), gll staging
__global__ __launch_bounds__(256, 4) void k_mfma(const ushort_t* __restrict__ Xb,
                                                 const ushort_t* __restrict__ Wb,
                                                 const float* __restrict__ bias,
                                                 ushort_t* __restrict__ Y16) {
    const int o0 = blockIdx.x * 128, r0 = blockIdx.y * 128;
    const int tid = threadIdx.x, w = tid >> 6, l = tid & 63;
    const int wm = w >> 1, wn = w & 1;
    __shared__ ushort_t xa[128 * 64];
    __shared__ ushort_t xw[128 * 64];
    f32x4 acc[4][4];
#pragma unroll
    for (int mf = 0; mf < 4; ++mf)
#pragma unroll
        for (int j = 0; j < 4; ++j) acc[mf][j] = (f32x4){0.f, 0.f, 0.f, 0.f};

    const ushort_t* Ab = Xb + (size_t)r0 * CIN;
    const ushort_t* Bb = Wb + (size_t)o0 * CIN;
    const int lrow = l >> 3, lch = (l & 7) * 8;

    for (int c0 = 0; c0 < CIN; c0 += 64) {
        if (c0) __syncthreads();
#pragma unroll
        for (int i = 0; i < 4; ++i) {
            int rowblk = (w * 4 + i) * 8;
            gll16(Ab + (size_t)(rowblk + lrow) * CIN + c0 + lch, xa + rowblk * 64);
        }
#pragma unroll
        for (int i = 0; i < 4; ++i) {
            int rowblk = (w * 4 + i) * 8;
            gll16(Bb + (size_t)(rowblk + lrow) * CIN + c0 + lch, xw + rowblk * 64);
        }
        __syncthreads();
#pragma unroll
        for (int kk = 0; kk < 2; ++kk) {
            bf16x8 bfrag[4];
#pragma unroll
            for (int j = 0; j < 4; ++j)
                bfrag[j] = *(const bf16x8*)(xw + (wn * 64 + j * 16 + (l & 15)) * 64 + kk * 32 + (l >> 4) * 8);
#pragma unroll
            for (int mf = 0; mf < 4; ++mf) {
                bf16x8 afrag = *(const bf16x8*)(xa + (wm * 64 + mf * 16 + (l & 15)) * 64 + kk * 32 + (l >> 4) * 8);
#pragma unroll
                for (int j = 0; j < 4; ++j)
                    acc[mf][j] = __builtin_amdgcn_mfma_f32_16x16x32_bf16(afrag, bfrag[j], acc[mf][j], 0, 0, 0);
            }
        }
    }
    // store bf16: lane l reg e -> row r0+wm*64+mf*16+(l>>4)*4+e, col o0+wn*64+j*16+(l&15)
    const int oc = l & 15, pq = (l >> 4) * 4;
#pragma unroll
    for (int j = 0; j < 4; ++j) {
        int o = o0 + wn * 64 + j * 16 + oc;
        float bo = bias[o];
#pragma unroll
        for (int mf = 0; mf < 4; ++mf) {
            int r = r0 + wm * 64 + mf * 16 + pq;    // 4 consecutive rows, same batch
            int b = r / PPAD;
            int p = r - b * PPAD;
            if (p < P) {
                ushort_t tmp[4];
#pragma unroll
                for (int e = 0; e < 4; ++e) tmp[e] = f2bf(acc[mf][j][e] + bo);
                *(ushort4*)(Y16 + ((size_t)b * 1024 + o) * P + p) = *(ushort4*)tmp;
            }
        }
    }
}

// ---------------- per-(b,n): k-norm, q-norm, Sq, and qh/qw partial sums (fused)
__global__ __launch_bounds__(256) void k_norm(const ushort_t* __restrict__ Y16,
                                              float* __restrict__ ink_g,
                                              float* __restrict__ sq_g,
                                              float* __restrict__ qh_g,
                                              float* __restrict__ qw_g) {
    const int bn = blockIdx.x, b = bn >> 3, n = bn & 7;
    const int tid = threadIdx.x;
    __shared__ ushort_t qs[64 * P];       // 25088 B
    __shared__ float inq_s[P];
    __shared__ float part[4][64];
    const uint* Yq = (const uint*)(Y16 + ((size_t)b * 1024 + n * 64) * P);
    for (int i = tid; i < 64 * (P / 2); i += 256) ((uint*)qs)[i] = Yq[i];
    // k-norm streamed from global (no reuse)
    const ushort_t* Yk = Y16 + ((size_t)b * 1024 + 512 + n * 64) * P;
    const int p = tid, pc = (p < P) ? p : 0;
    float sk = 0.f;
    for (int d = 0; d < 64; ++d) { float v = bf2f(Yk[d * P + pc]); sk = fmaf(v, v, sk); }
    __syncthreads();
    float sq = 0.f;
    for (int d = 0; d < 64; ++d) { float v = bf2f(qs[d * P + pc]); sq = fmaf(v, v, sq); }
    if (p < P) { ink_g[bn * P + p] = rsqrtf(sk); inq_s[p] = rsqrtf(sq); }
    __syncthreads();
    // Sq[d] = sum_p q_norm: thread (d, quarter)
    {
        int d = tid & 63, q4 = tid >> 6;
        float s = 0.f;
        for (int i = 0; i < 49; ++i) {
            int pp = q4 * 49 + i;
            s = fmaf(bf2f(qs[d * P + pp]), inq_s[pp], s);
        }
        part[q4][d] = s;
    }
    __syncthreads();
    if (tid < 64) sq_g[bn * 64 + tid] = part[0][tid] + part[1][tid] + part[2][tid] + part[3][tid];
    // qh[x][d] += sum_y q /8 ; qw[y][d] += sum_x q /8  (raw q, cross-n via global atomics)
    for (int it = tid; it < 896; it += 256) {
        int d = it & 63, xx = it >> 6;
        float s = 0.f;
#pragma unroll
        for (int y = 0; y < WW; ++y) s += bf2f(qs[d * P + xx * WW + y]);
        atomicAdd(&qh_g[(b * HH + xx) * 64 + d], s * 0.125f);
    }
    for (int it = tid; it < 896; it += 256) {
        int d = it & 63, y = it >> 6;
        float s = 0.f;
#pragma unroll
        for (int xx = 0; xx < HH; ++xx) s += bf2f(qs[d * P + xx * WW + y]);
        atomicAdd(&qw_g[(b * WW + y) * 64 + d], s * 0.125f);
    }
}

// ---------------- per-b: Aw[X], Ah[X] (parallel over (X, y/x) pairs)
__global__ __launch_bounds__(512) void k_rel(const float* __restrict__ qh_g,
                                             const float* __restrict__ qw_g,
                                             const float* __restrict__ relw,
                                             const float* __restrict__ relh,
                                             float* __restrict__ Aw_g,
                                             float* __restrict__ Ah_g) {
    const int b = blockIdx.x, t = threadIdx.x;
    if (t < 196) {
        int X = t / 14, y = t % 14;
        const float* qw = qw_g + (b * WW + y) * 64;
        const float* rw = relw + (13 + X - y) * 64;
        float s = 0.f;
#pragma unroll 8
        for (int d = 0; d < 64; ++d) s = fmaf(qw[d], rw[d], s);
        atomicAdd(&Aw_g[b * WW + X], s);
    } else if (t >= 256 && t < 452) {
        int i = t - 256, X = i / 14, xr = i % 14;
        const float* qh = qh_g + (b * HH + xr) * 64;
        const float* rh = relh + (13 + X - xr) * 64;
        float s = 0.f;
#pragma unroll 8
        for (int d = 0; d < 64; ++d) s = fmaf(qh[d], rh[d], s);
        atomicAdd(&Ah_g[b * HH + X], s);
    }
}

// ---------------- per-(b,n): partial dot -> atomicAdd into ml[b,p]
__global__ __launch_bounds__(256) void k_dot(const ushort_t* __restrict__ Y16,
                                             const float* __restrict__ ink_g,
                                             const float* __restrict__ sq_g,
                                             const int*   __restrict__ pair,
                                             float* __restrict__ ml) {
    const int bn = blockIdx.x, b = bn >> 3, n = bn & 7;
    const int tid = threadIdx.x;
    __shared__ float Sav[64];
    if (tid < 64) {
        int pb = pair[b];
        Sav[tid] = 0.5f * (sq_g[bn * 64 + tid] + sq_g[(pb * 8 + n) * 64 + tid]);
    }
    __syncthreads();
    const int p = tid;
    if (p < P) {
        const ushort_t* Yk = Y16 + ((size_t)b * 1024 + 512 + n * 64) * P;
        float s = 0.f;
#pragma unroll 8
        for (int d = 0; d < 64; ++d) s = fmaf(Sav[d], bf2f(Yk[d * P + p]), s);
        atomicAdd(&ml[b * P + p], s * ink_g[bn * P + p]);
    }
}

// ---------------- per-b: softmax((ml + Ah + Aw)/1568) -> attn
__global__ __launch_bounds__(256) void k_soft(const float* __restrict__ ml,
                                              const float* __restrict__ Aw_g,
                                              const float* __restrict__ Ah_g,
                                              float* __restrict__ attn_g) {
    const int b = blockIdx.x, tid = threadIdx.x;
    __shared__ float red[256];
    const int p = tid;
    float v = -1e30f;
    if (p < P) v = (ml[b * P + p] + Ah_g[b * HH + p / WW] + Aw_g[b * WW + p % WW]) * (1.f / 1568.f);
    red[tid] = v; __syncthreads();
    for (int s = 128; s > 0; s >>= 1) { if (tid < s) red[tid] = fmaxf(red[tid], red[tid + s]); __syncthreads(); }
    float mx = red[0]; __syncthreads();
    float e = (p < P) ? expf(v - mx) : 0.f;
    red[tid] = e; __syncthreads();
    for (int s = 128; s > 0; s >>= 1) { if (tid < s) red[tid] += red[tid + s]; __syncthreads(); }
    if (p < P) attn_g[b * P + p] = e / red[0];
}

// ---------------- out = concat(x/49, x*attn)
__global__ __launch_bounds__(256) void k_out(const float* __restrict__ x,
                                             const float* __restrict__ attn_g,
                                             float* __restrict__ out) {
    const int total4 = BATCH * CIN * P / 4;
    const int stride = gridDim.x * 256;
    const float4* x4 = (const float4*)x;
    const float4* a4 = (const float4*)attn_g;
    float4* o4 = (float4*)out;
    for (int i4 = blockIdx.x * 256 + threadIdx.x; i4 < total4; i4 += stride) {
        int i = i4 * 4;
        int b = i / (CIN * P);
        int r = i - b * (CIN * P);
        int p0 = r % P;
        float4 xv = x4[i4];
        float4 at = a4[(b * P + p0) >> 2];
        float4 o1 = make_float4(xv.x * (1.f/49.f), xv.y * (1.f/49.f),
                                xv.z * (1.f/49.f), xv.w * (1.f/49.f));
        float4 o2 = make_float4(xv.x * at.x, xv.y * at.y, xv.z * at.z, xv.w * at.w);
        o4[(b * (2 * CIN * P) + r) >> 2] = o1;
        o4[(b * (2 * CIN * P) + CIN * P + r) >> 2] = o2;
    }
}

extern "C" void kernel_launch(void* const* d_in, const int* in_sizes, int n_in,
                              void* d_out, int out_size, void* d_ws, size_t ws_size,
                              hipStream_t stream) {
    const float* x    = (const float*)d_in[0];
    const float* Wq   = (const float*)d_in[1];
    const float* bias = (const float*)d_in[2];
    const float* relw = (const float*)d_in[3];
    const float* relh = (const float*)d_in[4];
    const int*   pair = (const int*)d_in[5];
    float* out = (float*)d_out;
    float* ws  = (float*)d_ws;

    ushort_t* Y16 = (ushort_t*)(ws + OFF_Y16);
    ushort_t* Xb  = (ushort_t*)(ws + OFF_XB);
    ushort_t* Wb  = (ushort_t*)(ws + OFF_WB);
    float* ink  = ws + OFF_INK;
    float* sq   = ws + OFF_SQ;
    float* qh   = ws + OFF_QH;
    float* qw   = ws + OFF_QW;
    float* Aw   = ws + OFF_AW;
    float* Ah   = ws + OFF_AH;
    float* ml   = ws + OFF_ML;
    float* attn = ws + OFF_ATTN;

    hipMemsetAsync(ws + OFF_QH, 0, ZERO_FLOATS * sizeof(float), stream);
    k_convW<<<1024, 256, 0, stream>>>(Wq, Wb);
    k_trans<<<dim3(16, 7, 64), 256, 0, stream>>>(x, Xb);
    k_mfma <<<dim3(8, 112), 256, 0, stream>>>(Xb, Wb, bias, Y16);
    k_norm <<<BATCH * NHEAD, 256, 0, stream>>>(Y16, ink, sq, qh, qw);
    k_rel  <<<BATCH, 512, 0, stream>>>(qh, qw, relw, relh, Aw, Ah);
    k_dot  <<<BATCH * NHEAD, 256, 0, stream>>>(Y16, ink, sq, pair, ml);
    k_soft <<<BATCH, 256, 0, stream>>>(ml, Aw, Ah, attn);
    k_out  <<<2048, 256, 0, stream>>>(x, attn, out);
}

// Round 7
// 118.647 us; speedup vs baseline: 10.4542x; 1.0905x over previous
//
#include <hip/hip_runtime.h>
#include <hip/hip_bf16.h>
#include <math.h>

typedef unsigned short ushort_t;
using bf16x8 = __attribute__((ext_vector_type(8))) short;
using f32x4  = __attribute__((ext_vector_type(4))) float;

#define BATCH 64
#define CIN   1024
#define HH    14
#define WW    14
#define P     196
#define NHEAD 8
#define DKH   64
#define PPAD  224      // padded p rows per batch; M_total = 64*224 = 14336

// ws layout (float indices) — every buffer fully overwritten each call (no zero-init needed)
#define OFF_Y16  0
#define N_Y16_F  6422528            // 64*1024*196 ushorts
#define OFF_XB   (OFF_Y16 + N_Y16_F)
#define N_XB_F   7340032            // 64*224*1024 ushorts
#define OFF_WB   (OFF_XB + N_XB_F)
#define N_WB_F   524288             // 1024*1024 ushorts
#define OFF_INK  (OFF_WB + N_WB_F)
#define N_INK    (BATCH*NHEAD*P)    // 100352
#define OFF_SQ   (OFF_INK + N_INK)
#define N_SQ     (BATCH*NHEAD*DKH)  // 32768
#define OFF_QHP  (OFF_SQ + N_SQ)
#define N_QHP    (BATCH*NHEAD*HH*DKH)  // 458752
#define OFF_QWP  (OFF_QHP + N_QHP)
#define N_QWP    (BATCH*NHEAD*WW*DKH)  // 458752
#define OFF_DOTP (OFF_QWP + N_QWP)
#define N_DOTP   (BATCH*NHEAD*P)    // 100352
#define OFF_ATTN (OFF_DOTP + N_DOTP)
#define N_ATTN   (BATCH*P)

__device__ __forceinline__ ushort_t f2bf(float f) {
    union { float f; unsigned u; } v; v.f = f;
    unsigned r = v.u + 0x7fffu + ((v.u >> 16) & 1u);   // RNE
    return (ushort_t)(r >> 16);
}
__device__ __forceinline__ float bf2f(ushort_t u) {
    union { unsigned u; float f; } v; v.u = ((unsigned)u) << 16; return v.f;
}
__device__ __forceinline__ void gll16(const ushort_t* g, ushort_t* l) {
    __builtin_amdgcn_global_load_lds(
        (const __attribute__((address_space(1))) void*)g,
        (__attribute__((address_space(3))) void*)l, 16, 0, 0);
}

// ---------------- W -> bf16 [o][c] (linear, k-contiguous)
__global__ __launch_bounds__(256) void k_convW(const float* __restrict__ Wq,
                                               ushort_t* __restrict__ Wb) {
    int i = blockIdx.x * 256 + threadIdx.x;
    const float4 v = ((const float4*)Wq)[i];
    ushort4 o;
    o.x = f2bf(v.x); o.y = f2bf(v.y); o.z = f2bf(v.z); o.w = f2bf(v.w);
    ((ushort4*)Wb)[i] = o;
}

// ---------------- x -> bf16 transposed Xb[b][p][c], p padded to 224 (zeros)
__global__ __launch_bounds__(256) void k_trans(const float* __restrict__ x,
                                               ushort_t* __restrict__ Xb) {
    const int c0 = blockIdx.x * 64, p0 = blockIdx.y * 32, b = blockIdx.z;
    const int t = threadIdx.x;
    __shared__ float tile[64][33];
    const float* xb = x + (size_t)b * (CIN * P);
#pragma unroll
    for (int it = 0; it < 8; ++it) {
        int idx = t + it * 256;
        int c_l = idx >> 5, p_l = idx & 31;
        int p = p0 + p_l;
        tile[c_l][p_l] = (p < P) ? xb[(size_t)(c0 + c_l) * P + p] : 0.f;
    }
    __syncthreads();
    int c_chunk = (t & 7) * 8, p_l = t >> 3;
    ushort_t buf[8];
#pragma unroll
    for (int e = 0; e < 8; ++e) buf[e] = f2bf(tile[c_chunk + e][p_l]);
    *(uint4*)(Xb + ((size_t)b * PPAD + p0 + p_l) * CIN + c0 + c_chunk) = *(uint4*)buf;
}

// ---------------- MFMA GEMM (m97 structure): C[r,o] = bias[o] + sum_c Xb[r,c]*Wb[o,c]
// flat rows r=b*224+p, M=14336; 128x128 tile, BK=64, 4 waves (2x2), gll staging
__global__ __launch_bounds__(256, 4) void k_mfma(const ushort_t* __restrict__ Xb,
                                                 const ushort_t* __restrict__ Wb,
                                                 const float* __restrict__ bias,
                                                 ushort_t* __restrict__ Y16) {
    const int o0 = blockIdx.x * 128, r0 = blockIdx.y * 128;
    const int tid = threadIdx.x, w = tid >> 6, l = tid & 63;
    const int wm = w >> 1, wn = w & 1;
    __shared__ ushort_t xa[128 * 64];
    __shared__ ushort_t xw[128 * 64];
    f32x4 acc[4][4];
#pragma unroll
    for (int mf = 0; mf < 4; ++mf)
#pragma unroll
        for (int j = 0; j < 4; ++j) acc[mf][j] = (f32x4){0.f, 0.f, 0.f, 0.f};

    const ushort_t* Ab = Xb + (size_t)r0 * CIN;
    const ushort_t* Bb = Wb + (size_t)o0 * CIN;
    const int lrow = l >> 3, lch = (l & 7) * 8;

    for (int c0 = 0; c0 < CIN; c0 += 64) {
        if (c0) __syncthreads();
#pragma unroll
        for (int i = 0; i < 4; ++i) {
            int rowblk = (w * 4 + i) * 8;
            gll16(Ab + (size_t)(rowblk + lrow) * CIN + c0 + lch, xa + rowblk * 64);
        }
#pragma unroll
        for (int i = 0; i < 4; ++i) {
            int rowblk = (w * 4 + i) * 8;
            gll16(Bb + (size_t)(rowblk + lrow) * CIN + c0 + lch, xw + rowblk * 64);
        }
        __syncthreads();
#pragma unroll
        for (int kk = 0; kk < 2; ++kk) {
            bf16x8 bfrag[4];
#pragma unroll
            for (int j = 0; j < 4; ++j)
                bfrag[j] = *(const bf16x8*)(xw + (wn * 64 + j * 16 + (l & 15)) * 64 + kk * 32 + (l >> 4) * 8);
#pragma unroll
            for (int mf = 0; mf < 4; ++mf) {
                bf16x8 afrag = *(const bf16x8*)(xa + (wm * 64 + mf * 16 + (l & 15)) * 64 + kk * 32 + (l >> 4) * 8);
#pragma unroll
                for (int j = 0; j < 4; ++j)
                    acc[mf][j] = __builtin_amdgcn_mfma_f32_16x16x32_bf16(afrag, bfrag[j], acc[mf][j], 0, 0, 0);
            }
        }
    }
    // store bf16: lane l reg e -> row r0+wm*64+mf*16+(l>>4)*4+e, col o0+wn*64+j*16+(l&15)
    const int oc = l & 15, pq = (l >> 4) * 4;
#pragma unroll
    for (int j = 0; j < 4; ++j) {
        int o = o0 + wn * 64 + j * 16 + oc;
        float bo = bias[o];
#pragma unroll
        for (int mf = 0; mf < 4; ++mf) {
            int r = r0 + wm * 64 + mf * 16 + pq;    // 4 consecutive rows, same batch
            int b = r / PPAD;
            int p = r - b * PPAD;
            if (p < P) {
                ushort_t tmp[4];
#pragma unroll
                for (int e = 0; e < 4; ++e) tmp[e] = f2bf(acc[mf][j][e] + bo);
                *(ushort4*)(Y16 + ((size_t)b * 1024 + o) * P + p) = *(ushort4*)tmp;
            }
        }
    }
}

// ---------------- per-(b,n): ink, Sq, and qh/qw PARTIALS (plain stores, no atomics)
__global__ __launch_bounds__(256) void k_norm(const ushort_t* __restrict__ Y16,
                                              float* __restrict__ ink_g,
                                              float* __restrict__ sq_g,
                                              float* __restrict__ qhp,
                                              float* __restrict__ qwp) {
    const int bn = blockIdx.x, b = bn >> 3, n = bn & 7;
    const int tid = threadIdx.x;
    __shared__ ushort_t qs[64 * P];       // 25088 B
    __shared__ float inq_s[P];
    __shared__ float part[4][64];
    const uint* Yq = (const uint*)(Y16 + ((size_t)b * 1024 + n * 64) * P);
    for (int i = tid; i < 64 * (P / 2); i += 256) ((uint*)qs)[i] = Yq[i];
    const ushort_t* Yk = Y16 + ((size_t)b * 1024 + 512 + n * 64) * P;
    const int p = tid, pc = (p < P) ? p : 0;
    float sk = 0.f;
    for (int d = 0; d < 64; ++d) { float v = bf2f(Yk[d * P + pc]); sk = fmaf(v, v, sk); }
    __syncthreads();
    float sq = 0.f;
    for (int d = 0; d < 64; ++d) { float v = bf2f(qs[d * P + pc]); sq = fmaf(v, v, sq); }
    if (p < P) { ink_g[bn * P + p] = rsqrtf(sk); inq_s[p] = rsqrtf(sq); }
    __syncthreads();
    {   // Sq[d] = sum_p q_norm
        int d = tid & 63, q4 = tid >> 6;
        float s = 0.f;
        for (int i = 0; i < 49; ++i) {
            int pp = q4 * 49 + i;
            s = fmaf(bf2f(qs[d * P + pp]), inq_s[pp], s);
        }
        part[q4][d] = s;
    }
    __syncthreads();
    if (tid < 64) sq_g[bn * 64 + tid] = part[0][tid] + part[1][tid] + part[2][tid] + part[3][tid];
    // qhp[bn][x][d] = sum_y q /8 ; qwp[bn][y][d] = sum_x q /8  (plain stores)
    for (int it = tid; it < 896; it += 256) {
        int d = it & 63, xx = it >> 6;
        float s = 0.f;
#pragma unroll
        for (int y = 0; y < WW; ++y) s += bf2f(qs[d * P + xx * WW + y]);
        qhp[bn * 896 + it] = s * 0.125f;
    }
    for (int it = tid; it < 896; it += 256) {
        int d = it & 63, y = it >> 6;
        float s = 0.f;
#pragma unroll
        for (int xx = 0; xx < HH; ++xx) s += bf2f(qs[d * P + xx * WW + y]);
        qwp[bn * 896 + it] = s * 0.125f;
    }
}

// ---------------- per-(b,n): dot partial -> dotp[bn][p] (plain store)
__global__ __launch_bounds__(256) void k_dot(const ushort_t* __restrict__ Y16,
                                             const float* __restrict__ ink_g,
                                             const float* __restrict__ sq_g,
                                             const int*   __restrict__ pair,
                                             float* __restrict__ dotp) {
    const int bn = blockIdx.x, b = bn >> 3, n = bn & 7;
    const int tid = threadIdx.x;
    __shared__ float Sav[64];
    if (tid < 64) {
        int pb = pair[b];
        Sav[tid] = 0.5f * (sq_g[bn * 64 + tid] + sq_g[(pb * 8 + n) * 64 + tid]);
    }
    __syncthreads();
    const int p = tid;
    if (p < P) {
        const ushort_t* Yk = Y16 + ((size_t)b * 1024 + 512 + n * 64) * P;
        float s = 0.f;
#pragma unroll 8
        for (int d = 0; d < 64; ++d) s = fmaf(Sav[d], bf2f(Yk[d * P + p]), s);
        dotp[bn * P + p] = s * ink_g[bn * P + p];
    }
}

// ---------------- per-b: sum partials, Aw/Ah, softmax -> attn (fused tail)
__global__ __launch_bounds__(256) void k_attn2(const float* __restrict__ dotp,
                                               const float* __restrict__ qhp,
                                               const float* __restrict__ qwp,
                                               const float* __restrict__ relw,
                                               const float* __restrict__ relh,
                                               float* __restrict__ attn_g) {
    const int b = blockIdx.x, tid = threadIdx.x;
    __shared__ float qhs[896], qws[896];
    __shared__ float Aw[WW], Ah[HH];
    __shared__ float red[256];
    for (int i = tid; i < 896; i += 256) {
        float sh = 0.f, sw = 0.f;
#pragma unroll
        for (int n = 0; n < 8; ++n) {
            sh += qhp[(size_t)(b * 8 + n) * 896 + i];
            sw += qwp[(size_t)(b * 8 + n) * 896 + i];
        }
        qhs[i] = sh; qws[i] = sw;
    }
    if (tid < WW) { Aw[tid] = 0.f; Ah[tid] = 0.f; }
    __syncthreads();
    if (tid < 196) {            // pair (X, y): X=tid/14, y=tid%14
        int X = tid / 14, y = tid % 14;
        const float* qp = &qws[y * 64];
        const float* rw = relw + (13 + X - y) * 64;
        float s = 0.f;
#pragma unroll 8
        for (int d = 0; d < 64; ++d) s = fmaf(qp[d], rw[d], s);
        atomicAdd(&Aw[X], s);
        const float* hp = &qhs[y * 64];          // y = source row xr
        const float* rh = relh + (13 + X - y) * 64;
        float s2 = 0.f;
#pragma unroll 8
        for (int d = 0; d < 64; ++d) s2 = fmaf(hp[d], rh[d], s2);
        atomicAdd(&Ah[X], s2);
    }
    __syncthreads();
    const int p = tid;
    float v = -1e30f;
    if (p < P) {
        float dot = 0.f;
#pragma unroll
        for (int n = 0; n < 8; ++n) dot += dotp[(size_t)(b * 8 + n) * P + p];
        v = (dot + Ah[p / WW] + Aw[p % WW]) * (1.f / 1568.f);
    }
    red[tid] = v; __syncthreads();
    for (int s = 128; s > 0; s >>= 1) { if (tid < s) red[tid] = fmaxf(red[tid], red[tid + s]); __syncthreads(); }
    float mx = red[0]; __syncthreads();
    float e = (p < P) ? expf(v - mx) : 0.f;
    red[tid] = e; __syncthreads();
    for (int s = 128; s > 0; s >>= 1) { if (tid < s) red[tid] += red[tid + s]; __syncthreads(); }
    if (p < P) attn_g[b * P + p] = e / red[0];
}

// ---------------- out = concat(x/49, x*attn)
__global__ __launch_bounds__(256) void k_out(const float* __restrict__ x,
                                             const float* __restrict__ attn_g,
                                             float* __restrict__ out) {
    const int total4 = BATCH * CIN * P / 4;
    const int stride = gridDim.x * 256;
    const float4* x4 = (const float4*)x;
    const float4* a4 = (const float4*)attn_g;
    float4* o4 = (float4*)out;
    for (int i4 = blockIdx.x * 256 + threadIdx.x; i4 < total4; i4 += stride) {
        int i = i4 * 4;
        int b = i / (CIN * P);
        int r = i - b * (CIN * P);
        int p0 = r % P;
        float4 xv = x4[i4];
        float4 at = a4[(b * P + p0) >> 2];
        float4 o1 = make_float4(xv.x * (1.f/49.f), xv.y * (1.f/49.f),
                                xv.z * (1.f/49.f), xv.w * (1.f/49.f));
        float4 o2 = make_float4(xv.x * at.x, xv.y * at.y, xv.z * at.z, xv.w * at.w);
        o4[(b * (2 * CIN * P) + r) >> 2] = o1;
        o4[(b * (2 * CIN * P) + CIN * P + r) >> 2] = o2;
    }
}

extern "C" void kernel_launch(void* const* d_in, const int* in_sizes, int n_in,
                              void* d_out, int out_size, void* d_ws, size_t ws_size,
                              hipStream_t stream) {
    const float* x    = (const float*)d_in[0];
    const float* Wq   = (const float*)d_in[1];
    const float* bias = (const float*)d_in[2];
    const float* relw = (const float*)d_in[3];
    const float* relh = (const float*)d_in[4];
    const int*   pair = (const int*)d_in[5];
    float* out = (float*)d_out;
    float* ws  = (float*)d_ws;

    ushort_t* Y16 = (ushort_t*)(ws + OFF_Y16);
    ushort_t* Xb  = (ushort_t*)(ws + OFF_XB);
    ushort_t* Wb  = (ushort_t*)(ws + OFF_WB);
    float* ink  = ws + OFF_INK;
    float* sq   = ws + OFF_SQ;
    float* qhp  = ws + OFF_QHP;
    float* qwp  = ws + OFF_QWP;
    float* dotp = ws + OFF_DOTP;
    float* attn = ws + OFF_ATTN;

    k_convW<<<1024, 256, 0, stream>>>(Wq, Wb);
    k_trans<<<dim3(16, 7, 64), 256, 0, stream>>>(x, Xb);
    k_mfma <<<dim3(8, 112), 256, 0, stream>>>(Xb, Wb, bias, Y16);
    k_norm <<<BATCH * NHEAD, 256, 0, stream>>>(Y16, ink, sq, qhp, qwp);
    k_dot  <<<BATCH * NHEAD, 256, 0, stream>>>(Y16, ink, sq, pair, dotp);
    k_attn2<<<BATCH, 256, 0, stream>>>(dotp, qhp, qwp, relw, relh, attn);
    k_out  <<<2048, 256, 0, stream>>>(x, attn, out);
}

// Round 8
// 114.938 us; speedup vs baseline: 10.7915x; 1.0323x over previous
//
#include <hip/hip_runtime.h>
#include <hip/hip_bf16.h>
#include <math.h>

typedef unsigned short ushort_t;
using bf16x8 = __attribute__((ext_vector_type(8))) short;
using f32x4  = __attribute__((ext_vector_type(4))) float;

#define BATCH 64
#define CIN   1024
#define HH    14
#define WW    14
#define P     196
#define NHEAD 8
#define DKH   64
#define PPAD  224      // padded p rows per batch; M_total = 64*224 = 14336

// ws layout (float indices) — every buffer fully overwritten each call
#define OFF_Y16  0
#define N_Y16_F  6422528            // 64*1024*196 ushorts
#define OFF_XB   (OFF_Y16 + N_Y16_F)
#define N_XB_F   7340032            // 64*224*1024 ushorts
#define OFF_WB   (OFF_XB + N_XB_F)
#define N_WB_F   524288             // 1024*1024 ushorts
#define OFF_QHP  (OFF_WB + N_WB_F)
#define N_QHP    (BATCH*NHEAD*HH*DKH)  // 458752
#define OFF_QWP  (OFF_QHP + N_QHP)
#define N_QWP    (BATCH*NHEAD*WW*DKH)  // 458752
#define OFF_DOTP (OFF_QWP + N_QWP)
#define N_DOTP   (BATCH*NHEAD*P)    // 100352
#define OFF_ATTN (OFF_DOTP + N_DOTP)
#define N_ATTN   (BATCH*P)

__device__ __forceinline__ ushort_t f2bf(float f) {
    union { float f; unsigned u; } v; v.f = f;
    unsigned r = v.u + 0x7fffu + ((v.u >> 16) & 1u);   // RNE
    return (ushort_t)(r >> 16);
}
__device__ __forceinline__ float bf2f(ushort_t u) {
    union { unsigned u; float f; } v; v.u = ((unsigned)u) << 16; return v.f;
}
__device__ __forceinline__ void gll16(const ushort_t* g, ushort_t* l) {
    __builtin_amdgcn_global_load_lds(
        (const __attribute__((address_space(1))) void*)g,
        (__attribute__((address_space(3))) void*)l, 16, 0, 0);
}

// ---------------- prep: W->bf16 (blocks 0..1023) ; x -> bf16 transposed Xb (rest)
__global__ __launch_bounds__(256) void k_prep(const float* __restrict__ x,
                                              const float* __restrict__ Wq,
                                              ushort_t* __restrict__ Xb,
                                              ushort_t* __restrict__ Wb) {
    if (blockIdx.x < 1024) {            // convW: 1024 blocks x 256 thr x 4 floats
        int i = blockIdx.x * 256 + threadIdx.x;
        const float4 v = ((const float4*)Wq)[i];
        ushort4 o;
        o.x = f2bf(v.x); o.y = f2bf(v.y); o.z = f2bf(v.z); o.w = f2bf(v.w);
        ((ushort4*)Wb)[i] = o;
        return;
    }
    const int idx = blockIdx.x - 1024;  // 0..7167 = 16 x 7 x 64
    const int c0 = (idx & 15) * 64;
    const int rest = idx >> 4;
    const int p0 = (rest % 7) * 32;
    const int b  = rest / 7;
    const int t = threadIdx.x;
    __shared__ float tile[64][33];
    const float* xb = x + (size_t)b * (CIN * P);
#pragma unroll
    for (int it = 0; it < 8; ++it) {
        int id2 = t + it * 256;
        int c_l = id2 >> 5, p_l = id2 & 31;
        int p = p0 + p_l;
        tile[c_l][p_l] = (p < P) ? xb[(size_t)(c0 + c_l) * P + p] : 0.f;
    }
    __syncthreads();
    int c_chunk = (t & 7) * 8, p_l = t >> 3;
    ushort_t buf[8];
#pragma unroll
    for (int e = 0; e < 8; ++e) buf[e] = f2bf(tile[c_chunk + e][p_l]);
    *(uint4*)(Xb + ((size_t)b * PPAD + p0 + p_l) * CIN + c0 + c_chunk) = *(uint4*)buf;
}

// ---------------- MFMA GEMM (m97 structure): C[r,o] = bias[o] + sum_c Xb[r,c]*Wb[o,c]
__global__ __launch_bounds__(256, 4) void k_mfma(const ushort_t* __restrict__ Xb,
                                                 const ushort_t* __restrict__ Wb,
                                                 const float* __restrict__ bias,
                                                 ushort_t* __restrict__ Y16) {
    const int o0 = blockIdx.x * 128, r0 = blockIdx.y * 128;
    const int tid = threadIdx.x, w = tid >> 6, l = tid & 63;
    const int wm = w >> 1, wn = w & 1;
    __shared__ ushort_t xa[128 * 64];
    __shared__ ushort_t xw[128 * 64];
    f32x4 acc[4][4];
#pragma unroll
    for (int mf = 0; mf < 4; ++mf)
#pragma unroll
        for (int j = 0; j < 4; ++j) acc[mf][j] = (f32x4){0.f, 0.f, 0.f, 0.f};

    const ushort_t* Ab = Xb + (size_t)r0 * CIN;
    const ushort_t* Bb = Wb + (size_t)o0 * CIN;
    const int lrow = l >> 3, lch = (l & 7) * 8;

    for (int c0 = 0; c0 < CIN; c0 += 64) {
        if (c0) __syncthreads();
#pragma unroll
        for (int i = 0; i < 4; ++i) {
            int rowblk = (w * 4 + i) * 8;
            gll16(Ab + (size_t)(rowblk + lrow) * CIN + c0 + lch, xa + rowblk * 64);
        }
#pragma unroll
        for (int i = 0; i < 4; ++i) {
            int rowblk = (w * 4 + i) * 8;
            gll16(Bb + (size_t)(rowblk + lrow) * CIN + c0 + lch, xw + rowblk * 64);
        }
        __syncthreads();
#pragma unroll
        for (int kk = 0; kk < 2; ++kk) {
            bf16x8 bfrag[4];
#pragma unroll
            for (int j = 0; j < 4; ++j)
                bfrag[j] = *(const bf16x8*)(xw + (wn * 64 + j * 16 + (l & 15)) * 64 + kk * 32 + (l >> 4) * 8);
#pragma unroll
            for (int mf = 0; mf < 4; ++mf) {
                bf16x8 afrag = *(const bf16x8*)(xa + (wm * 64 + mf * 16 + (l & 15)) * 64 + kk * 32 + (l >> 4) * 8);
#pragma unroll
                for (int j = 0; j < 4; ++j)
                    acc[mf][j] = __builtin_amdgcn_mfma_f32_16x16x32_bf16(afrag, bfrag[j], acc[mf][j], 0, 0, 0);
            }
        }
    }
    const int oc = l & 15, pq = (l >> 4) * 4;
#pragma unroll
    for (int j = 0; j < 4; ++j) {
        int o = o0 + wn * 64 + j * 16 + oc;
        float bo = bias[o];
#pragma unroll
        for (int mf = 0; mf < 4; ++mf) {
            int r = r0 + wm * 64 + mf * 16 + pq;
            int b = r / PPAD;
            int p = r - b * PPAD;
            if (p < P) {
                ushort_t tmp[4];
#pragma unroll
                for (int e = 0; e < 4; ++e) tmp[e] = f2bf(acc[mf][j][e] + bo);
                *(ushort4*)(Y16 + ((size_t)b * 1024 + o) * P + p) = *(ushort4*)tmp;
            }
        }
    }
}

// ---------------- per-(b,n): norms (own + pair, redundant), Sav, dot, qh/qw partials
__global__ __launch_bounds__(256) void k_normdot(const ushort_t* __restrict__ Y16,
                                                 const int*   __restrict__ pair,
                                                 float* __restrict__ qhp,
                                                 float* __restrict__ qwp,
                                                 float* __restrict__ dotp) {
    const int bn = blockIdx.x, b = bn >> 3, n = bn & 7;
    const int tid = threadIdx.x;
    __shared__ ushort_t qs[64 * P];       // own q head  (25088 B)
    __shared__ ushort_t qp[64 * P];       // pair q head (25088 B)
    __shared__ float inq_s[P], inqp_s[P];
    __shared__ float part[4][64];
    __shared__ float Sav[64];
    const int pb = pair[b];
    const uint* Yq  = (const uint*)(Y16 + ((size_t)b  * 1024 + n * 64) * P);
    const uint* Yqp = (const uint*)(Y16 + ((size_t)pb * 1024 + n * 64) * P);
    for (int i = tid; i < 64 * (P / 2); i += 256) {
        ((uint*)qs)[i] = Yq[i];
        ((uint*)qp)[i] = Yqp[i];
    }
    // k-norm (streamed from global; Y16 k-half is L2-warm)
    const ushort_t* Yk = Y16 + ((size_t)b * 1024 + 512 + n * 64) * P;
    const int p = tid, pc = (p < P) ? p : 0;
    float sk = 0.f;
    for (int d = 0; d < 64; ++d) { float v = bf2f(Yk[d * P + pc]); sk = fmaf(v, v, sk); }
    const float inkp = rsqrtf(sk);        // kept in register for the dot below
    __syncthreads();
    float sq = 0.f, sqp = 0.f;
    for (int d = 0; d < 64; ++d) {
        float v = bf2f(qs[d * P + pc]); sq  = fmaf(v, v, sq);
        float u = bf2f(qp[d * P + pc]); sqp = fmaf(u, u, sqp);
    }
    if (p < P) { inq_s[p] = rsqrtf(sq); inqp_s[p] = rsqrtf(sqp); }
    __syncthreads();
    {   // part[q4][d] = quarter-sums of (qn_own + qn_pair)
        int d = tid & 63, q4 = tid >> 6;
        float s = 0.f;
        for (int i = 0; i < 49; ++i) {
            int pp = q4 * 49 + i;
            s = fmaf(bf2f(qs[d * P + pp]), inq_s[pp], s);
            s = fmaf(bf2f(qp[d * P + pp]), inqp_s[pp], s);
        }
        part[q4][d] = s;
    }
    __syncthreads();
    if (tid < 64)
        Sav[tid] = 0.5f * (part[0][tid] + part[1][tid] + part[2][tid] + part[3][tid]);
    __syncthreads();
    // dot partial (Yk re-read hits L2)
    if (p < P) {
        float s = 0.f;
#pragma unroll 8
        for (int d = 0; d < 64; ++d) s = fmaf(Sav[d], bf2f(Yk[d * P + p]), s);
        dotp[bn * P + p] = s * inkp;
    }
    // qh/qw partials (own q only)
    for (int it = tid; it < 896; it += 256) {
        int d = it & 63, xx = it >> 6;
        float s = 0.f;
#pragma unroll
        for (int y = 0; y < WW; ++y) s += bf2f(qs[d * P + xx * WW + y]);
        qhp[bn * 896 + it] = s * 0.125f;
    }
    for (int it = tid; it < 896; it += 256) {
        int d = it & 63, y = it >> 6;
        float s = 0.f;
#pragma unroll
        for (int xx = 0; xx < HH; ++xx) s += bf2f(qs[d * P + xx * WW + y]);
        qwp[bn * 896 + it] = s * 0.125f;
    }
}

// ---------------- per-b: sum partials, Aw/Ah, softmax -> attn (fused tail)
__global__ __launch_bounds__(256) void k_attn2(const float* __restrict__ dotp,
                                               const float* __restrict__ qhp,
                                               const float* __restrict__ qwp,
                                               const float* __restrict__ relw,
                                               const float* __restrict__ relh,
                                               float* __restrict__ attn_g) {
    const int b = blockIdx.x, tid = threadIdx.x;
    __shared__ float qhs[896], qws[896];
    __shared__ float Aw[WW], Ah[HH];
    __shared__ float red[256];
    for (int i = tid; i < 896; i += 256) {
        float sh = 0.f, sw = 0.f;
#pragma unroll
        for (int n = 0; n < 8; ++n) {
            sh += qhp[(size_t)(b * 8 + n) * 896 + i];
            sw += qwp[(size_t)(b * 8 + n) * 896 + i];
        }
        qhs[i] = sh; qws[i] = sw;
    }
    if (tid < WW) { Aw[tid] = 0.f; Ah[tid] = 0.f; }
    __syncthreads();
    if (tid < 196) {            // pair (X, y): X=tid/14, y=tid%14
        int X = tid / 14, y = tid % 14;
        const float* qp = &qws[y * 64];
        const float* rw = relw + (13 + X - y) * 64;
        float s = 0.f;
#pragma unroll 8
        for (int d = 0; d < 64; ++d) s = fmaf(qp[d], rw[d], s);
        atomicAdd(&Aw[X], s);
        const float* hp = &qhs[y * 64];          // y = source row xr
        const float* rh = relh + (13 + X - y) * 64;
        float s2 = 0.f;
#pragma unroll 8
        for (int d = 0; d < 64; ++d) s2 = fmaf(hp[d], rh[d], s2);
        atomicAdd(&Ah[X], s2);
    }
    __syncthreads();
    const int p = tid;
    float v = -1e30f;
    if (p < P) {
        float dot = 0.f;
#pragma unroll
        for (int n = 0; n < 8; ++n) dot += dotp[(size_t)(b * 8 + n) * P + p];
        v = (dot + Ah[p / WW] + Aw[p % WW]) * (1.f / 1568.f);
    }
    red[tid] = v; __syncthreads();
    for (int s = 128; s > 0; s >>= 1) { if (tid < s) red[tid] = fmaxf(red[tid], red[tid + s]); __syncthreads(); }
    float mx = red[0]; __syncthreads();
    float e = (p < P) ? expf(v - mx) : 0.f;
    red[tid] = e; __syncthreads();
    for (int s = 128; s > 0; s >>= 1) { if (tid < s) red[tid] += red[tid + s]; __syncthreads(); }
    if (p < P) attn_g[b * P + p] = e / red[0];
}

// ---------------- out = concat(x/49, x*attn)
__global__ __launch_bounds__(256) void k_out(const float* __restrict__ x,
                                             const float* __restrict__ attn_g,
                                             float* __restrict__ out) {
    const int total4 = BATCH * CIN * P / 4;
    const int stride = gridDim.x * 256;
    const float4* x4 = (const float4*)x;
    const float4* a4 = (const float4*)attn_g;
    float4* o4 = (float4*)out;
    for (int i4 = blockIdx.x * 256 + threadIdx.x; i4 < total4; i4 += stride) {
        int i = i4 * 4;
        int b = i / (CIN * P);
        int r = i - b * (CIN * P);
        int p0 = r % P;
        float4 xv = x4[i4];
        float4 at = a4[(b * P + p0) >> 2];
        float4 o1 = make_float4(xv.x * (1.f/49.f), xv.y * (1.f/49.f),
                                xv.z * (1.f/49.f), xv.w * (1.f/49.f));
        float4 o2 = make_float4(xv.x * at.x, xv.y * at.y, xv.z * at.z, xv.w * at.w);
        o4[(b * (2 * CIN * P) + r) >> 2] = o1;
        o4[(b * (2 * CIN * P) + CIN * P + r) >> 2] = o2;
    }
}

extern "C" void kernel_launch(void* const* d_in, const int* in_sizes, int n_in,
                              void* d_out, int out_size, void* d_ws, size_t ws_size,
                              hipStream_t stream) {
    const float* x    = (const float*)d_in[0];
    const float* Wq   = (const float*)d_in[1];
    const float* bias = (const float*)d_in[2];
    const float* relw = (const float*)d_in[3];
    const float* relh = (const float*)d_in[4];
    const int*   pair = (const int*)d_in[5];
    float* out = (float*)d_out;
    float* ws  = (float*)d_ws;

    ushort_t* Y16 = (ushort_t*)(ws + OFF_Y16);
    ushort_t* Xb  = (ushort_t*)(ws + OFF_XB);
    ushort_t* Wb  = (ushort_t*)(ws + OFF_WB);
    float* qhp  = ws + OFF_QHP;
    float* qwp  = ws + OFF_QWP;
    float* dotp = ws + OFF_DOTP;
    float* attn = ws + OFF_ATTN;

    k_prep   <<<8192, 256, 0, stream>>>(x, Wq, Xb, Wb);
    k_mfma   <<<dim3(8, 112), 256, 0, stream>>>(Xb, Wb, bias, Y16);
    k_normdot<<<BATCH * NHEAD, 256, 0, stream>>>(Y16, pair, qhp, qwp, dotp);
    k_attn2  <<<BATCH, 256, 0, stream>>>(dotp, qhp, qwp, relw, relh, attn);
    k_out    <<<2048, 256, 0, stream>>>(x, attn, out);
}

// Round 9
// 110.127 us; speedup vs baseline: 11.2629x; 1.0437x over previous
//
#include <hip/hip_runtime.h>
#include <hip/hip_bf16.h>
#include <math.h>

typedef unsigned short ushort_t;
using bf16x8 = __attribute__((ext_vector_type(8))) short;
using f32x4  = __attribute__((ext_vector_type(4))) float;

#define BATCH 64
#define CIN   1024
#define HH    14
#define WW    14
#define P     196
#define NHEAD 8
#define DKH   64
#define PPAD  224      // padded p rows per batch; M_total = 64*224 = 14336

// ws layout (float indices) — every buffer fully overwritten each call
#define OFF_Y16  0
#define N_Y16_F  6422528            // 64*1024*196 ushorts
#define OFF_XB   (OFF_Y16 + N_Y16_F)
#define N_XB_F   7340032            // 64*224*1024 ushorts
#define OFF_WB   (OFF_XB + N_XB_F)
#define N_WB_F   524288             // 1024*1024 ushorts
#define OFF_QHP  (OFF_WB + N_WB_F)
#define N_QHP    (BATCH*NHEAD*HH*DKH)  // 458752
#define OFF_QWP  (OFF_QHP + N_QHP)
#define N_QWP    (BATCH*NHEAD*WW*DKH)  // 458752
#define OFF_DOTP (OFF_QWP + N_QWP)
#define N_DOTP   (BATCH*NHEAD*P)    // 100352
#define OFF_ATTN (OFF_DOTP + N_DOTP)
#define N_ATTN   (BATCH*P)

__device__ __forceinline__ ushort_t f2bf(float f) {
    union { float f; unsigned u; } v; v.f = f;
    unsigned r = v.u + 0x7fffu + ((v.u >> 16) & 1u);   // RNE
    return (ushort_t)(r >> 16);
}
__device__ __forceinline__ float bf2f(ushort_t u) {
    union { unsigned u; float f; } v; v.u = ((unsigned)u) << 16; return v.f;
}
__device__ __forceinline__ void gll16(const ushort_t* g, ushort_t* l) {
    __builtin_amdgcn_global_load_lds(
        (const __attribute__((address_space(1))) void*)g,
        (__attribute__((address_space(3))) void*)l, 16, 0, 0);
}

// ---------------- prep: W->bf16 (blocks 0..1023) ; x -> bf16 transposed Xb (rest)
__global__ __launch_bounds__(256) void k_prep(const float* __restrict__ x,
                                              const float* __restrict__ Wq,
                                              ushort_t* __restrict__ Xb,
                                              ushort_t* __restrict__ Wb) {
    if (blockIdx.x < 1024) {            // convW: 1024 blocks x 256 thr x 4 floats
        int i = blockIdx.x * 256 + threadIdx.x;
        const float4 v = ((const float4*)Wq)[i];
        ushort4 o;
        o.x = f2bf(v.x); o.y = f2bf(v.y); o.z = f2bf(v.z); o.w = f2bf(v.w);
        ((ushort4*)Wb)[i] = o;
        return;
    }
    const int idx = blockIdx.x - 1024;  // 0..7167 = 16 x 7 x 64
    const int c0 = (idx & 15) * 64;
    const int rest = idx >> 4;
    const int p0 = (rest % 7) * 32;
    const int b  = rest / 7;
    const int t = threadIdx.x;
    __shared__ float tile[64][33];
    const float* xb = x + (size_t)b * (CIN * P);
#pragma unroll
    for (int it = 0; it < 8; ++it) {
        int id2 = t + it * 256;
        int c_l = id2 >> 5, p_l = id2 & 31;
        int p = p0 + p_l;
        tile[c_l][p_l] = (p < P) ? xb[(size_t)(c0 + c_l) * P + p] : 0.f;
    }
    __syncthreads();
    int c_chunk = (t & 7) * 8, p_l = t >> 3;
    ushort_t buf[8];
#pragma unroll
    for (int e = 0; e < 8; ++e) buf[e] = f2bf(tile[c_chunk + e][p_l]);
    *(uint4*)(Xb + ((size_t)b * PPAD + p0 + p_l) * CIN + c0 + c_chunk) = *(uint4*)buf;
}

// ---------------- MFMA GEMM (m97 structure + T1 XCD swizzle)
// C[r,o] = bias[o] + sum_c Xb[r,c]*Wb[o,c];  grid = 896 flat blocks.
// Swizzle: xcd = bid&7 gets chunk of 112 logical tiles -> the 8 o-blocks
// sharing one A row-panel all land on ONE XCD (A fetched once per L2).
__global__ __launch_bounds__(256, 4) void k_mfma(const ushort_t* __restrict__ Xb,
                                                 const ushort_t* __restrict__ Wb,
                                                 const float* __restrict__ bias,
                                                 ushort_t* __restrict__ Y16) {
    const int bid = blockIdx.x;                 // 0..895
    const int f = (bid & 7) * 112 + (bid >> 3); // bijective (896 % 8 == 0)
    const int o0 = (f & 7) * 128, r0 = (f >> 3) * 128;
    const int tid = threadIdx.x, w = tid >> 6, l = tid & 63;
    const int wm = w >> 1, wn = w & 1;
    __shared__ ushort_t xa[128 * 64];
    __shared__ ushort_t xw[128 * 64];
    f32x4 acc[4][4];
#pragma unroll
    for (int mf = 0; mf < 4; ++mf)
#pragma unroll
        for (int j = 0; j < 4; ++j) acc[mf][j] = (f32x4){0.f, 0.f, 0.f, 0.f};

    const ushort_t* Ab = Xb + (size_t)r0 * CIN;
    const ushort_t* Bb = Wb + (size_t)o0 * CIN;
    const int lrow = l >> 3, lch = (l & 7) * 8;

    for (int c0 = 0; c0 < CIN; c0 += 64) {
        if (c0) __syncthreads();
#pragma unroll
        for (int i = 0; i < 4; ++i) {
            int rowblk = (w * 4 + i) * 8;
            gll16(Ab + (size_t)(rowblk + lrow) * CIN + c0 + lch, xa + rowblk * 64);
        }
#pragma unroll
        for (int i = 0; i < 4; ++i) {
            int rowblk = (w * 4 + i) * 8;
            gll16(Bb + (size_t)(rowblk + lrow) * CIN + c0 + lch, xw + rowblk * 64);
        }
        __syncthreads();
#pragma unroll
        for (int kk = 0; kk < 2; ++kk) {
            bf16x8 bfrag[4];
#pragma unroll
            for (int j = 0; j < 4; ++j)
                bfrag[j] = *(const bf16x8*)(xw + (wn * 64 + j * 16 + (l & 15)) * 64 + kk * 32 + (l >> 4) * 8);
#pragma unroll
            for (int mf = 0; mf < 4; ++mf) {
                bf16x8 afrag = *(const bf16x8*)(xa + (wm * 64 + mf * 16 + (l & 15)) * 64 + kk * 32 + (l >> 4) * 8);
#pragma unroll
                for (int j = 0; j < 4; ++j)
                    acc[mf][j] = __builtin_amdgcn_mfma_f32_16x16x32_bf16(afrag, bfrag[j], acc[mf][j], 0, 0, 0);
            }
        }
    }
    const int oc = l & 15, pq = (l >> 4) * 4;
#pragma unroll
    for (int j = 0; j < 4; ++j) {
        int o = o0 + wn * 64 + j * 16 + oc;
        float bo = bias[o];
#pragma unroll
        for (int mf = 0; mf < 4; ++mf) {
            int r = r0 + wm * 64 + mf * 16 + pq;
            int b = r / PPAD;
            int p = r - b * PPAD;
            if (p < P) {
                ushort_t tmp[4];
#pragma unroll
                for (int e = 0; e < 4; ++e) tmp[e] = f2bf(acc[mf][j][e] + bo);
                *(ushort4*)(Y16 + ((size_t)b * 1024 + o) * P + p) = *(ushort4*)tmp;
            }
        }
    }
}

// ---------------- per-(b,n): norms (own + pair, redundant), Sav, dot, qh/qw partials
__global__ __launch_bounds__(256) void k_normdot(const ushort_t* __restrict__ Y16,
                                                 const int*   __restrict__ pair,
                                                 float* __restrict__ qhp,
                                                 float* __restrict__ qwp,
                                                 float* __restrict__ dotp) {
    const int bn = blockIdx.x, b = bn >> 3, n = bn & 7;
    const int tid = threadIdx.x;
    __shared__ ushort_t qs[64 * P];       // own q head  (25088 B)
    __shared__ ushort_t qp[64 * P];       // pair q head (25088 B)
    __shared__ float inq_s[P], inqp_s[P];
    __shared__ float part[4][64];
    __shared__ float Sav[64];
    const int pb = pair[b];
    const uint* Yq  = (const uint*)(Y16 + ((size_t)b  * 1024 + n * 64) * P);
    const uint* Yqp = (const uint*)(Y16 + ((size_t)pb * 1024 + n * 64) * P);
    for (int i = tid; i < 64 * (P / 2); i += 256) {
        ((uint*)qs)[i] = Yq[i];
        ((uint*)qp)[i] = Yqp[i];
    }
    // k-norm (streamed from global; Y16 k-half is L2-warm)
    const ushort_t* Yk = Y16 + ((size_t)b * 1024 + 512 + n * 64) * P;
    const int p = tid, pc = (p < P) ? p : 0;
    float sk = 0.f;
    for (int d = 0; d < 64; ++d) { float v = bf2f(Yk[d * P + pc]); sk = fmaf(v, v, sk); }
    const float inkp = rsqrtf(sk);        // kept in register for the dot below
    __syncthreads();
    float sq = 0.f, sqp = 0.f;
    for (int d = 0; d < 64; ++d) {
        float v = bf2f(qs[d * P + pc]); sq  = fmaf(v, v, sq);
        float u = bf2f(qp[d * P + pc]); sqp = fmaf(u, u, sqp);
    }
    if (p < P) { inq_s[p] = rsqrtf(sq); inqp_s[p] = rsqrtf(sqp); }
    __syncthreads();
    {   // part[q4][d] = quarter-sums of (qn_own + qn_pair)
        int d = tid & 63, q4 = tid >> 6;
        float s = 0.f;
        for (int i = 0; i < 49; ++i) {
            int pp = q4 * 49 + i;
            s = fmaf(bf2f(qs[d * P + pp]), inq_s[pp], s);
            s = fmaf(bf2f(qp[d * P + pp]), inqp_s[pp], s);
        }
        part[q4][d] = s;
    }
    __syncthreads();
    if (tid < 64)
        Sav[tid] = 0.5f * (part[0][tid] + part[1][tid] + part[2][tid] + part[3][tid]);
    __syncthreads();
    // dot partial (Yk re-read hits L2)
    if (p < P) {
        float s = 0.f;
#pragma unroll 8
        for (int d = 0; d < 64; ++d) s = fmaf(Sav[d], bf2f(Yk[d * P + p]), s);
        dotp[bn * P + p] = s * inkp;
    }
    // qh/qw partials (own q only)
    for (int it = tid; it < 896; it += 256) {
        int d = it & 63, xx = it >> 6;
        float s = 0.f;
#pragma unroll
        for (int y = 0; y < WW; ++y) s += bf2f(qs[d * P + xx * WW + y]);
        qhp[bn * 896 + it] = s * 0.125f;
    }
    for (int it = tid; it < 896; it += 256) {
        int d = it & 63, y = it >> 6;
        float s = 0.f;
#pragma unroll
        for (int xx = 0; xx < HH; ++xx) s += bf2f(qs[d * P + xx * WW + y]);
        qwp[bn * 896 + it] = s * 0.125f;
    }
}

// ---------------- per-b: sum partials, Aw/Ah, softmax -> attn (fused tail)
__global__ __launch_bounds__(256) void k_attn2(const float* __restrict__ dotp,
                                               const float* __restrict__ qhp,
                                               const float* __restrict__ qwp,
                                               const float* __restrict__ relw,
                                               const float* __restrict__ relh,
                                               float* __restrict__ attn_g) {
    const int b = blockIdx.x, tid = threadIdx.x;
    __shared__ float qhs[896], qws[896];
    __shared__ float Aw[WW], Ah[HH];
    __shared__ float red[256];
    for (int i = tid; i < 896; i += 256) {
        float sh = 0.f, sw = 0.f;
#pragma unroll
        for (int n = 0; n < 8; ++n) {
            sh += qhp[(size_t)(b * 8 + n) * 896 + i];
            sw += qwp[(size_t)(b * 8 + n) * 896 + i];
        }
        qhs[i] = sh; qws[i] = sw;
    }
    if (tid < WW) { Aw[tid] = 0.f; Ah[tid] = 0.f; }
    __syncthreads();
    if (tid < 196) {            // pair (X, y): X=tid/14, y=tid%14
        int X = tid / 14, y = tid % 14;
        const float* qp = &qws[y * 64];
        const float* rw = relw + (13 + X - y) * 64;
        float s = 0.f;
#pragma unroll 8
        for (int d = 0; d < 64; ++d) s = fmaf(qp[d], rw[d], s);
        atomicAdd(&Aw[X], s);
        const float* hp = &qhs[y * 64];          // y = source row xr
        const float* rh = relh + (13 + X - y) * 64;
        float s2 = 0.f;
#pragma unroll 8
        for (int d = 0; d < 64; ++d) s2 = fmaf(hp[d], rh[d], s2);
        atomicAdd(&Ah[X], s2);
    }
    __syncthreads();
    const int p = tid;
    float v = -1e30f;
    if (p < P) {
        float dot = 0.f;
#pragma unroll
        for (int n = 0; n < 8; ++n) dot += dotp[(size_t)(b * 8 + n) * P + p];
        v = (dot + Ah[p / WW] + Aw[p % WW]) * (1.f / 1568.f);
    }
    red[tid] = v; __syncthreads();
    for (int s = 128; s > 0; s >>= 1) { if (tid < s) red[tid] = fmaxf(red[tid], red[tid + s]); __syncthreads(); }
    float mx = red[0]; __syncthreads();
    float e = (p < P) ? expf(v - mx) : 0.f;
    red[tid] = e; __syncthreads();
    for (int s = 128; s > 0; s >>= 1) { if (tid < s) red[tid] += red[tid + s]; __syncthreads(); }
    if (p < P) attn_g[b * P + p] = e / red[0];
}

// ---------------- out = concat(x/49, x*attn)
__global__ __launch_bounds__(256) void k_out(const float* __restrict__ x,
                                             const float* __restrict__ attn_g,
                                             float* __restrict__ out) {
    const int total4 = BATCH * CIN * P / 4;
    const int stride = gridDim.x * 256;
    const float4* x4 = (const float4*)x;
    const float4* a4 = (const float4*)attn_g;
    float4* o4 = (float4*)out;
    for (int i4 = blockIdx.x * 256 + threadIdx.x; i4 < total4; i4 += stride) {
        int i = i4 * 4;
        int b = i / (CIN * P);
        int r = i - b * (CIN * P);
        int p0 = r % P;
        float4 xv = x4[i4];
        float4 at = a4[(b * P + p0) >> 2];
        float4 o1 = make_float4(xv.x * (1.f/49.f), xv.y * (1.f/49.f),
                                xv.z * (1.f/49.f), xv.w * (1.f/49.f));
        float4 o2 = make_float4(xv.x * at.x, xv.y * at.y, xv.z * at.z, xv.w * at.w);
        o4[(b * (2 * CIN * P) + r) >> 2] = o1;
        o4[(b * (2 * CIN * P) + CIN * P + r) >> 2] = o2;
    }
}

extern "C" void kernel_launch(void* const* d_in, const int* in_sizes, int n_in,
                              void* d_out, int out_size, void* d_ws, size_t ws_size,
                              hipStream_t stream) {
    const float* x    = (const float*)d_in[0];
    const float* Wq   = (const float*)d_in[1];
    const float* bias = (const float*)d_in[2];
    const float* relw = (const float*)d_in[3];
    const float* relh = (const float*)d_in[4];
    const int*   pair = (const int*)d_in[5];
    float* out = (float*)d_out;
    float* ws  = (float*)d_ws;

    ushort_t* Y16 = (ushort_t*)(ws + OFF_Y16);
    ushort_t* Xb  = (ushort_t*)(ws + OFF_XB);
    ushort_t* Wb  = (ushort_t*)(ws + OFF_WB);
    float* qhp  = ws + OFF_QHP;
    float* qwp  = ws + OFF_QWP;
    float* dotp = ws + OFF_DOTP;
    float* attn = ws + OFF_ATTN;

    k_prep   <<<8192, 256, 0, stream>>>(x, Wq, Xb, Wb);
    k_mfma   <<<896, 256, 0, stream>>>(Xb, Wb, bias, Y16);
    k_normdot<<<BATCH * NHEAD, 256, 0, stream>>>(Y16, pair, qhp, qwp, dotp);
    k_attn2  <<<BATCH, 256, 0, stream>>>(dotp, qhp, qwp, relw, relh, attn);
    k_out    <<<2048, 256, 0, stream>>>(x, attn, out);
}

// Round 10
// 109.170 us; speedup vs baseline: 11.3616x; 1.0088x over previous
//
#include <hip/hip_runtime.h>
#include <hip/hip_bf16.h>
#include <math.h>

typedef unsigned short ushort_t;
using bf16x8 = __attribute__((ext_vector_type(8))) short;
using f32x4  = __attribute__((ext_vector_type(4))) float;

#define BATCH 64
#define CIN   1024
#define HH    14
#define WW    14
#define P     196
#define NHEAD 8
#define DKH   64
#define PPAD  224      // padded p rows per batch; M_total = 64*224 = 14336

// ws layout (float indices) — every buffer fully overwritten each call
#define OFF_Y16  0
#define N_Y16_F  6422528            // 64*1024*196 ushorts
#define OFF_XB   (OFF_Y16 + N_Y16_F)
#define N_XB_F   7340032            // 64*224*1024 ushorts
#define OFF_WB   (OFF_XB + N_XB_F)
#define N_WB_F   524288             // 1024*1024 ushorts
#define OFF_QHP  (OFF_WB + N_WB_F)
#define N_QHP    (BATCH*NHEAD*HH*DKH)  // 458752
#define OFF_QWP  (OFF_QHP + N_QHP)
#define N_QWP    (BATCH*NHEAD*WW*DKH)  // 458752
#define OFF_DOTP (OFF_QWP + N_QWP)
#define N_DOTP   (BATCH*NHEAD*P)    // 100352
#define OFF_ATTN (OFF_DOTP + N_DOTP)
#define N_ATTN   (BATCH*P)

__device__ __forceinline__ ushort_t f2bf(float f) {
    union { float f; unsigned u; } v; v.f = f;
    unsigned r = v.u + 0x7fffu + ((v.u >> 16) & 1u);   // RNE
    return (ushort_t)(r >> 16);
}
__device__ __forceinline__ float bf2f(ushort_t u) {
    union { unsigned u; float f; } v; v.u = ((unsigned)u) << 16; return v.f;
}
__device__ __forceinline__ void gll16(const ushort_t* g, ushort_t* l) {
    __builtin_amdgcn_global_load_lds(
        (const __attribute__((address_space(1))) void*)g,
        (__attribute__((address_space(3))) void*)l, 16, 0, 0);
}

// ---------------- prep: W->bf16 (blocks 0..1023) ; x -> bf16 transposed Xb (rest)
__global__ __launch_bounds__(256) void k_prep(const float* __restrict__ x,
                                              const float* __restrict__ Wq,
                                              ushort_t* __restrict__ Xb,
                                              ushort_t* __restrict__ Wb) {
    if (blockIdx.x < 1024) {            // convW: 1024 blocks x 256 thr x 4 floats
        int i = blockIdx.x * 256 + threadIdx.x;
        const float4 v = ((const float4*)Wq)[i];
        ushort4 o;
        o.x = f2bf(v.x); o.y = f2bf(v.y); o.z = f2bf(v.z); o.w = f2bf(v.w);
        ((ushort4*)Wb)[i] = o;
        return;
    }
    const int idx = blockIdx.x - 1024;  // 0..7167 = 16 x 7 x 64
    const int c0 = (idx & 15) * 64;
    const int rest = idx >> 4;
    const int p0 = (rest % 7) * 32;
    const int b  = rest / 7;
    const int t = threadIdx.x;
    __shared__ float tile[64][33];
    const float* xb = x + (size_t)b * (CIN * P);
#pragma unroll
    for (int it = 0; it < 8; ++it) {
        int id2 = t + it * 256;
        int c_l = id2 >> 5, p_l = id2 & 31;
        int p = p0 + p_l;
        tile[c_l][p_l] = (p < P) ? xb[(size_t)(c0 + c_l) * P + p] : 0.f;
    }
    __syncthreads();
    int c_chunk = (t & 7) * 8, p_l = t >> 3;
    ushort_t buf[8];
#pragma unroll
    for (int e = 0; e < 8; ++e) buf[e] = f2bf(tile[c_chunk + e][p_l]);
    *(uint4*)(Xb + ((size_t)b * PPAD + p0 + p_l) * CIN + c0 + c_chunk) = *(uint4*)buf;
}

// ---------------- MFMA GEMM (m97 structure + T1 XCD swizzle)
__global__ __launch_bounds__(256, 4) void k_mfma(const ushort_t* __restrict__ Xb,
                                                 const ushort_t* __restrict__ Wb,
                                                 const float* __restrict__ bias,
                                                 ushort_t* __restrict__ Y16) {
    const int bid = blockIdx.x;                 // 0..895
    const int f = (bid & 7) * 112 + (bid >> 3); // bijective (896 % 8 == 0)
    const int o0 = (f & 7) * 128, r0 = (f >> 3) * 128;
    const int tid = threadIdx.x, w = tid >> 6, l = tid & 63;
    const int wm = w >> 1, wn = w & 1;
    __shared__ ushort_t xa[128 * 64];
    __shared__ ushort_t xw[128 * 64];
    f32x4 acc[4][4];
#pragma unroll
    for (int mf = 0; mf < 4; ++mf)
#pragma unroll
        for (int j = 0; j < 4; ++j) acc[mf][j] = (f32x4){0.f, 0.f, 0.f, 0.f};

    const ushort_t* Ab = Xb + (size_t)r0 * CIN;
    const ushort_t* Bb = Wb + (size_t)o0 * CIN;
    const int lrow = l >> 3, lch = (l & 7) * 8;

    for (int c0 = 0; c0 < CIN; c0 += 64) {
        if (c0) __syncthreads();
#pragma unroll
        for (int i = 0; i < 4; ++i) {
            int rowblk = (w * 4 + i) * 8;
            gll16(Ab + (size_t)(rowblk + lrow) * CIN + c0 + lch, xa + rowblk * 64);
        }
#pragma unroll
        for (int i = 0; i < 4; ++i) {
            int rowblk = (w * 4 + i) * 8;
            gll16(Bb + (size_t)(rowblk + lrow) * CIN + c0 + lch, xw + rowblk * 64);
        }
        __syncthreads();
#pragma unroll
        for (int kk = 0; kk < 2; ++kk) {
            bf16x8 bfrag[4];
#pragma unroll
            for (int j = 0; j < 4; ++j)
                bfrag[j] = *(const bf16x8*)(xw + (wn * 64 + j * 16 + (l & 15)) * 64 + kk * 32 + (l >> 4) * 8);
#pragma unroll
            for (int mf = 0; mf < 4; ++mf) {
                bf16x8 afrag = *(const bf16x8*)(xa + (wm * 64 + mf * 16 + (l & 15)) * 64 + kk * 32 + (l >> 4) * 8);
#pragma unroll
                for (int j = 0; j < 4; ++j)
                    acc[mf][j] = __builtin_amdgcn_mfma_f32_16x16x32_bf16(afrag, bfrag[j], acc[mf][j], 0, 0, 0);
            }
        }
    }
    const int oc = l & 15, pq = (l >> 4) * 4;
#pragma unroll
    for (int j = 0; j < 4; ++j) {
        int o = o0 + wn * 64 + j * 16 + oc;
        float bo = bias[o];
#pragma unroll
        for (int mf = 0; mf < 4; ++mf) {
            int r = r0 + wm * 64 + mf * 16 + pq;
            int b = r / PPAD;
            int p = r - b * PPAD;
            if (p < P) {
                ushort_t tmp[4];
#pragma unroll
                for (int e = 0; e < 4; ++e) tmp[e] = f2bf(acc[mf][j][e] + bo);
                *(ushort4*)(Y16 + ((size_t)b * 1024 + o) * P + p) = *(ushort4*)tmp;
            }
        }
    }
}

// ---------------- per-(b,n): LDS-staged norms (own+pair), Sav, dot, qh/qw partials
// All three operands loaded via uint4 (16B/lane coalesced); k read ONCE from global.
__global__ __launch_bounds__(256) void k_normdot(const ushort_t* __restrict__ Y16,
                                                 const int*   __restrict__ pair,
                                                 float* __restrict__ qhp,
                                                 float* __restrict__ qwp,
                                                 float* __restrict__ dotp) {
    const int bn = blockIdx.x, b = bn >> 3, n = bn & 7;
    const int tid = threadIdx.x;
    __shared__ ushort_t qs[64 * P];       // own q head  (25088 B)
    __shared__ ushort_t qp[64 * P];       // pair q head (25088 B)
    __shared__ ushort_t ks[64 * P];       // k head      (25088 B)
    __shared__ float inq_s[P], inqp_s[P];
    __shared__ float part[4][64];
    __shared__ float Sav[64];
    const int pb = pair[b];
    const uint4* Yq  = (const uint4*)(Y16 + ((size_t)b  * 1024 + n * 64) * P);
    const uint4* Yqp = (const uint4*)(Y16 + ((size_t)pb * 1024 + n * 64) * P);
    const uint4* Yk  = (const uint4*)(Y16 + ((size_t)b  * 1024 + 512 + n * 64) * P);
    for (int i = tid; i < 1568; i += 256) {     // 1568 uint4 = 64*196 bf16
        ((uint4*)qs)[i] = Yq[i];
        ((uint4*)qp)[i] = Yqp[i];
        ((uint4*)ks)[i] = Yk[i];
    }
    __syncthreads();
    const int p = tid, pc = (p < P) ? p : 0;
    float sk = 0.f, sq = 0.f, sqp = 0.f;
    for (int d = 0; d < 64; ++d) {
        float kv = bf2f(ks[d * P + pc]); sk  = fmaf(kv, kv, sk);
        float v  = bf2f(qs[d * P + pc]); sq  = fmaf(v, v, sq);
        float u  = bf2f(qp[d * P + pc]); sqp = fmaf(u, u, sqp);
    }
    const float inkp = rsqrtf(sk);
    if (p < P) { inq_s[p] = rsqrtf(sq); inqp_s[p] = rsqrtf(sqp); }
    __syncthreads();
    {   // part[q4][d] = quarter-sums of (qn_own + qn_pair)
        int d = tid & 63, q4 = tid >> 6;
        float s = 0.f;
        for (int i = 0; i < 49; ++i) {
            int pp = q4 * 49 + i;
            s = fmaf(bf2f(qs[d * P + pp]), inq_s[pp], s);
            s = fmaf(bf2f(qp[d * P + pp]), inqp_s[pp], s);
        }
        part[q4][d] = s;
    }
    __syncthreads();
    if (tid < 64)
        Sav[tid] = 0.5f * (part[0][tid] + part[1][tid] + part[2][tid] + part[3][tid]);
    __syncthreads();
    if (p < P) {
        float s = 0.f;
#pragma unroll 8
        for (int d = 0; d < 64; ++d) s = fmaf(Sav[d], bf2f(ks[d * P + p]), s);
        dotp[bn * P + p] = s * inkp;
    }
    // qh/qw partials (own q only)
    for (int it = tid; it < 896; it += 256) {
        int d = it & 63, xx = it >> 6;
        float s = 0.f;
#pragma unroll
        for (int y = 0; y < WW; ++y) s += bf2f(qs[d * P + xx * WW + y]);
        qhp[bn * 896 + it] = s * 0.125f;
    }
    for (int it = tid; it < 896; it += 256) {
        int d = it & 63, y = it >> 6;
        float s = 0.f;
#pragma unroll
        for (int xx = 0; xx < HH; ++xx) s += bf2f(qs[d * P + xx * WW + y]);
        qwp[bn * 896 + it] = s * 0.125f;
    }
}

// ---------------- per-b: sum partials, Aw/Ah, softmax -> attn (fused tail)
__global__ __launch_bounds__(256) void k_attn2(const float* __restrict__ dotp,
                                               const float* __restrict__ qhp,
                                               const float* __restrict__ qwp,
                                               const float* __restrict__ relw,
                                               const float* __restrict__ relh,
                                               float* __restrict__ attn_g) {
    const int b = blockIdx.x, tid = threadIdx.x;
    __shared__ float qhs[896], qws[896];
    __shared__ float Aw[WW], Ah[HH];
    __shared__ float red[256];
    for (int i = tid; i < 896; i += 256) {
        float sh = 0.f, sw = 0.f;
#pragma unroll
        for (int n = 0; n < 8; ++n) {
            sh += qhp[(size_t)(b * 8 + n) * 896 + i];
            sw += qwp[(size_t)(b * 8 + n) * 896 + i];
        }
        qhs[i] = sh; qws[i] = sw;
    }
    if (tid < WW) { Aw[tid] = 0.f; Ah[tid] = 0.f; }
    __syncthreads();
    if (tid < 196) {            // pair (X, y): X=tid/14, y=tid%14
        int X = tid / 14, y = tid % 14;
        const float* qp = &qws[y * 64];
        const float* rw = relw + (13 + X - y) * 64;
        float s = 0.f;
#pragma unroll 8
        for (int d = 0; d < 64; ++d) s = fmaf(qp[d], rw[d], s);
        atomicAdd(&Aw[X], s);
        const float* hp = &qhs[y * 64];          // y = source row xr
        const float* rh = relh + (13 + X - y) * 64;
        float s2 = 0.f;
#pragma unroll 8
        for (int d = 0; d < 64; ++d) s2 = fmaf(hp[d], rh[d], s2);
        atomicAdd(&Ah[X], s2);
    }
    __syncthreads();
    const int p = tid;
    float v = -1e30f;
    if (p < P) {
        float dot = 0.f;
#pragma unroll
        for (int n = 0; n < 8; ++n) dot += dotp[(size_t)(b * 8 + n) * P + p];
        v = (dot + Ah[p / WW] + Aw[p % WW]) * (1.f / 1568.f);
    }
    red[tid] = v; __syncthreads();
    for (int s = 128; s > 0; s >>= 1) { if (tid < s) red[tid] = fmaxf(red[tid], red[tid + s]); __syncthreads(); }
    float mx = red[0]; __syncthreads();
    float e = (p < P) ? expf(v - mx) : 0.f;
    red[tid] = e; __syncthreads();
    for (int s = 128; s > 0; s >>= 1) { if (tid < s) red[tid] += red[tid + s]; __syncthreads(); }
    if (p < P) attn_g[b * P + p] = e / red[0];
}

// ---------------- out = concat(x/49, x*attn)
__global__ __launch_bounds__(256) void k_out(const float* __restrict__ x,
                                             const float* __restrict__ attn_g,
                                             float* __restrict__ out) {
    const int total4 = BATCH * CIN * P / 4;
    const int stride = gridDim.x * 256;
    const float4* x4 = (const float4*)x;
    const float4* a4 = (const float4*)attn_g;
    float4* o4 = (float4*)out;
    for (int i4 = blockIdx.x * 256 + threadIdx.x; i4 < total4; i4 += stride) {
        int i = i4 * 4;
        int b = i / (CIN * P);
        int r = i - b * (CIN * P);
        int p0 = r % P;
        float4 xv = x4[i4];
        float4 at = a4[(b * P + p0) >> 2];
        float4 o1 = make_float4(xv.x * (1.f/49.f), xv.y * (1.f/49.f),
                                xv.z * (1.f/49.f), xv.w * (1.f/49.f));
        float4 o2 = make_float4(xv.x * at.x, xv.y * at.y, xv.z * at.z, xv.w * at.w);
        o4[(b * (2 * CIN * P) + r) >> 2] = o1;
        o4[(b * (2 * CIN * P) + CIN * P + r) >> 2] = o2;
    }
}

extern "C" void kernel_launch(void* const* d_in, const int* in_sizes, int n_in,
                              void* d_out, int out_size, void* d_ws, size_t ws_size,
                              hipStream_t stream) {
    const float* x    = (const float*)d_in[0];
    const float* Wq   = (const float*)d_in[1];
    const float* bias = (const float*)d_in[2];
    const float* relw = (const float*)d_in[3];
    const float* relh = (const float*)d_in[4];
    const int*   pair = (const int*)d_in[5];
    float* out = (float*)d_out;
    float* ws  = (float*)d_ws;

    ushort_t* Y16 = (ushort_t*)(ws + OFF_Y16);
    ushort_t* Xb  = (ushort_t*)(ws + OFF_XB);
    ushort_t* Wb  = (ushort_t*)(ws + OFF_WB);
    float* qhp  = ws + OFF_QHP;
    float* qwp  = ws + OFF_QWP;
    float* dotp = ws + OFF_DOTP;
    float* attn = ws + OFF_ATTN;

    k_prep   <<<8192, 256, 0, stream>>>(x, Wq, Xb, Wb);
    k_mfma   <<<896, 256, 0, stream>>>(Xb, Wb, bias, Y16);
    k_normdot<<<BATCH * NHEAD, 256, 0, stream>>>(Y16, pair, qhp, qwp, dotp);
    k_attn2  <<<BATCH, 256, 0, stream>>>(dotp, qhp, qwp, relw, relh, attn);
    k_out    <<<2048, 256, 0, stream>>>(x, attn, out);
}

// Round 11
// 104.816 us; speedup vs baseline: 11.8336x; 1.0415x over previous
//
#include <hip/hip_runtime.h>
#include <hip/hip_bf16.h>
#include <math.h>

typedef unsigned short ushort_t;
using bf16x8 = __attribute__((ext_vector_type(8))) short;
using f32x4  = __attribute__((ext_vector_type(4))) float;

#define BATCH 64
#define CIN   1024
#define HH    14
#define WW    14
#define P     196
#define NHEAD 8
#define DKH   64
// M_total = 64*196 = 12544 = 98 tiles of 128 (NO padding — 196%4==0 keeps
// every aligned 4-row store group inside one batch)

// ws layout (float indices) — every buffer fully overwritten each call
#define OFF_Y16  0
#define N_Y16_F  6422528            // 64*1024*196 ushorts
#define OFF_XB   (OFF_Y16 + N_Y16_F)
#define N_XB_F   6422528            // 64*196*1024 ushorts (unpadded)
#define OFF_WB   (OFF_XB + N_XB_F)
#define N_WB_F   524288             // 1024*1024 ushorts
#define OFF_QHP  (OFF_WB + N_WB_F)
#define N_QHP    (BATCH*NHEAD*HH*DKH)  // 458752
#define OFF_QWP  (OFF_QHP + N_QHP)
#define N_QWP    (BATCH*NHEAD*WW*DKH)  // 458752
#define OFF_DOTP (OFF_QWP + N_QWP)
#define N_DOTP   (BATCH*NHEAD*P)    // 100352
#define OFF_ATTN (OFF_DOTP + N_DOTP)
#define N_ATTN   (BATCH*P)

__device__ __forceinline__ ushort_t f2bf(float f) {
    union { float f; unsigned u; } v; v.f = f;
    unsigned r = v.u + 0x7fffu + ((v.u >> 16) & 1u);   // RNE
    return (ushort_t)(r >> 16);
}
__device__ __forceinline__ float bf2f(ushort_t u) {
    union { unsigned u; float f; } v; v.u = ((unsigned)u) << 16; return v.f;
}
__device__ __forceinline__ void gll16(const ushort_t* g, ushort_t* l) {
    __builtin_amdgcn_global_load_lds(
        (const __attribute__((address_space(1))) void*)g,
        (__attribute__((address_space(3))) void*)l, 16, 0, 0);
}

// ---------------- prep: W->bf16 (blocks 0..1023) ; x -> bf16 transposed Xb (rest)
// x-transpose tile: [64 c][28 p] (196 = 7*28, no pad rows, no guards)
__global__ __launch_bounds__(256) void k_prep(const float* __restrict__ x,
                                              const float* __restrict__ Wq,
                                              ushort_t* __restrict__ Xb,
                                              ushort_t* __restrict__ Wb) {
    if (blockIdx.x < 1024) {            // convW: rows 0..1023 of W (q,k only)
        int i = blockIdx.x * 256 + threadIdx.x;
        const float4 v = ((const float4*)Wq)[i];
        ushort4 o;
        o.x = f2bf(v.x); o.y = f2bf(v.y); o.z = f2bf(v.z); o.w = f2bf(v.w);
        ((ushort4*)Wb)[i] = o;
        return;
    }
    const int idx = blockIdx.x - 1024;  // 0..7167 = 16 ctiles x 7 ptiles x 64 b
    const int c0 = (idx & 15) * 64;
    const int rest = idx >> 4;          // 0..447
    const int p0 = (rest % 7) * 28;
    const int b  = rest / 7;
    const int t = threadIdx.x;
    __shared__ float tile[64][33];      // odd pitch -> conflict-free transpose read
    const float* xb = x + (size_t)b * (CIN * P);
    for (int id = t; id < 448; id += 256) {      // 448 float4 = 64 rows x 7
        int c_l = id / 7, f4 = id - c_l * 7;
        float4 v = *(const float4*)(xb + (size_t)(c0 + c_l) * P + p0 + f4 * 4);
        tile[c_l][f4 * 4 + 0] = v.x; tile[c_l][f4 * 4 + 1] = v.y;
        tile[c_l][f4 * 4 + 2] = v.z; tile[c_l][f4 * 4 + 3] = v.w;
    }
    __syncthreads();
    if (t < 224) {                      // 28 p-rows x 8 c-chunks
        int c_chunk = (t & 7) * 8, p_l = t >> 3;
        ushort_t buf[8];
#pragma unroll
        for (int e = 0; e < 8; ++e) buf[e] = f2bf(tile[c_chunk + e][p_l]);
        *(uint4*)(Xb + ((size_t)b * P + p0 + p_l) * CIN + c0 + c_chunk) = *(uint4*)buf;
    }
}

// ---------------- MFMA GEMM (m97 structure + T1 XCD swizzle), M=12544 unpadded
__global__ __launch_bounds__(256, 4) void k_mfma(const ushort_t* __restrict__ Xb,
                                                 const ushort_t* __restrict__ Wb,
                                                 const float* __restrict__ bias,
                                                 ushort_t* __restrict__ Y16) {
    const int bid = blockIdx.x;                 // 0..783
    const int f = (bid & 7) * 98 + (bid >> 3);  // bijective (784 = 8*98)
    const int o0 = (f & 7) * 128, r0 = (f >> 3) * 128;
    const int tid = threadIdx.x, w = tid >> 6, l = tid & 63;
    const int wm = w >> 1, wn = w & 1;
    __shared__ ushort_t xa[128 * 64];
    __shared__ ushort_t xw[128 * 64];
    f32x4 acc[4][4];
#pragma unroll
    for (int mf = 0; mf < 4; ++mf)
#pragma unroll
        for (int j = 0; j < 4; ++j) acc[mf][j] = (f32x4){0.f, 0.f, 0.f, 0.f};

    const ushort_t* Ab = Xb + (size_t)r0 * CIN;
    const ushort_t* Bb = Wb + (size_t)o0 * CIN;
    const int lrow = l >> 3, lch = (l & 7) * 8;

    for (int c0 = 0; c0 < CIN; c0 += 64) {
        if (c0) __syncthreads();
#pragma unroll
        for (int i = 0; i < 4; ++i) {
            int rowblk = (w * 4 + i) * 8;
            gll16(Ab + (size_t)(rowblk + lrow) * CIN + c0 + lch, xa + rowblk * 64);
        }
#pragma unroll
        for (int i = 0; i < 4; ++i) {
            int rowblk = (w * 4 + i) * 8;
            gll16(Bb + (size_t)(rowblk + lrow) * CIN + c0 + lch, xw + rowblk * 64);
        }
        __syncthreads();
#pragma unroll
        for (int kk = 0; kk < 2; ++kk) {
            bf16x8 bfrag[4];
#pragma unroll
            for (int j = 0; j < 4; ++j)
                bfrag[j] = *(const bf16x8*)(xw + (wn * 64 + j * 16 + (l & 15)) * 64 + kk * 32 + (l >> 4) * 8);
#pragma unroll
            for (int mf = 0; mf < 4; ++mf) {
                bf16x8 afrag = *(const bf16x8*)(xa + (wm * 64 + mf * 16 + (l & 15)) * 64 + kk * 32 + (l >> 4) * 8);
#pragma unroll
                for (int j = 0; j < 4; ++j)
                    acc[mf][j] = __builtin_amdgcn_mfma_f32_16x16x32_bf16(afrag, bfrag[j], acc[mf][j], 0, 0, 0);
            }
        }
    }
    // r = flat row = b*196 + p; r%4==0 group stays in one batch (196%4==0)
    const int oc = l & 15, pq = (l >> 4) * 4;
#pragma unroll
    for (int j = 0; j < 4; ++j) {
        int o = o0 + wn * 64 + j * 16 + oc;
        float bo = bias[o];
#pragma unroll
        for (int mf = 0; mf < 4; ++mf) {
            int r = r0 + wm * 64 + mf * 16 + pq;
            int b = r / P;
            int p = r - b * P;
            ushort_t tmp[4];
#pragma unroll
            for (int e = 0; e < 4; ++e) tmp[e] = f2bf(acc[mf][j][e] + bo);
            *(ushort4*)(Y16 + ((size_t)b * 1024 + o) * P + p) = *(ushort4*)tmp;
        }
    }
}

// ---------------- per-(b,n): LDS-staged norms (own+pair), Sav, dot, qh/qw partials
__global__ __launch_bounds__(256) void k_normdot(const ushort_t* __restrict__ Y16,
                                                 const int*   __restrict__ pair,
                                                 float* __restrict__ qhp,
                                                 float* __restrict__ qwp,
                                                 float* __restrict__ dotp) {
    const int bn = blockIdx.x, b = bn >> 3, n = bn & 7;
    const int tid = threadIdx.x;
    __shared__ ushort_t qs[64 * P];       // own q head  (25088 B)
    __shared__ ushort_t qp[64 * P];       // pair q head (25088 B)
    __shared__ ushort_t ks[64 * P];       // k head      (25088 B)
    __shared__ float inq_s[P], inqp_s[P];
    __shared__ float part[4][64];
    __shared__ float Sav[64];
    const int pb = pair[b];
    const uint4* Yq  = (const uint4*)(Y16 + ((size_t)b  * 1024 + n * 64) * P);
    const uint4* Yqp = (const uint4*)(Y16 + ((size_t)pb * 1024 + n * 64) * P);
    const uint4* Yk  = (const uint4*)(Y16 + ((size_t)b  * 1024 + 512 + n * 64) * P);
    for (int i = tid; i < 1568; i += 256) {     // 1568 uint4 = 64*196 bf16
        ((uint4*)qs)[i] = Yq[i];
        ((uint4*)qp)[i] = Yqp[i];
        ((uint4*)ks)[i] = Yk[i];
    }
    __syncthreads();
    const int p = tid, pc = (p < P) ? p : 0;
    float sk = 0.f, sq = 0.f, sqp = 0.f;
    for (int d = 0; d < 64; ++d) {
        float kv = bf2f(ks[d * P + pc]); sk  = fmaf(kv, kv, sk);
        float v  = bf2f(qs[d * P + pc]); sq  = fmaf(v, v, sq);
        float u  = bf2f(qp[d * P + pc]); sqp = fmaf(u, u, sqp);
    }
    const float inkp = rsqrtf(sk);
    if (p < P) { inq_s[p] = rsqrtf(sq); inqp_s[p] = rsqrtf(sqp); }
    __syncthreads();
    {   // part[q4][d] = quarter-sums of (qn_own + qn_pair)
        int d = tid & 63, q4 = tid >> 6;
        float s = 0.f;
        for (int i = 0; i < 49; ++i) {
            int pp = q4 * 49 + i;
            s = fmaf(bf2f(qs[d * P + pp]), inq_s[pp], s);
            s = fmaf(bf2f(qp[d * P + pp]), inqp_s[pp], s);
        }
        part[q4][d] = s;
    }
    __syncthreads();
    if (tid < 64)
        Sav[tid] = 0.5f * (part[0][tid] + part[1][tid] + part[2][tid] + part[3][tid]);
    __syncthreads();
    if (p < P) {
        float s = 0.f;
#pragma unroll 8
        for (int d = 0; d < 64; ++d) s = fmaf(Sav[d], bf2f(ks[d * P + p]), s);
        dotp[bn * P + p] = s * inkp;
    }
    // qh/qw partials (own q only)
    for (int it = tid; it < 896; it += 256) {
        int d = it & 63, xx = it >> 6;
        float s = 0.f;
#pragma unroll
        for (int y = 0; y < WW; ++y) s += bf2f(qs[d * P + xx * WW + y]);
        qhp[bn * 896 + it] = s * 0.125f;
    }
    for (int it = tid; it < 896; it += 256) {
        int d = it & 63, y = it >> 6;
        float s = 0.f;
#pragma unroll
        for (int xx = 0; xx < HH; ++xx) s += bf2f(qs[d * P + xx * WW + y]);
        qwp[bn * 896 + it] = s * 0.125f;
    }
}

// ---------------- per-b: sum partials, Aw/Ah, softmax -> attn (fused tail)
__global__ __launch_bounds__(256) void k_attn2(const float* __restrict__ dotp,
                                               const float* __restrict__ qhp,
                                               const float* __restrict__ qwp,
                                               const float* __restrict__ relw,
                                               const float* __restrict__ relh,
                                               float* __restrict__ attn_g) {
    const int b = blockIdx.x, tid = threadIdx.x;
    __shared__ float qhs[896], qws[896];
    __shared__ float Aw[WW], Ah[HH];
    __shared__ float red[256];
    for (int i = tid; i < 896; i += 256) {
        float sh = 0.f, sw = 0.f;
#pragma unroll
        for (int n = 0; n < 8; ++n) {
            sh += qhp[(size_t)(b * 8 + n) * 896 + i];
            sw += qwp[(size_t)(b * 8 + n) * 896 + i];
        }
        qhs[i] = sh; qws[i] = sw;
    }
    if (tid < WW) { Aw[tid] = 0.f; Ah[tid] = 0.f; }
    __syncthreads();
    if (tid < 196) {            // pair (X, y): X=tid/14, y=tid%14
        int X = tid / 14, y = tid % 14;
        const float* qp = &qws[y * 64];
        const float* rw = relw + (13 + X - y) * 64;
        float s = 0.f;
#pragma unroll 8
        for (int d = 0; d < 64; ++d) s = fmaf(qp[d], rw[d], s);
        atomicAdd(&Aw[X], s);
        const float* hp = &qhs[y * 64];          // y = source row xr
        const float* rh = relh + (13 + X - y) * 64;
        float s2 = 0.f;
#pragma unroll 8
        for (int d = 0; d < 64; ++d) s2 = fmaf(hp[d], rh[d], s2);
        atomicAdd(&Ah[X], s2);
    }
    __syncthreads();
    const int p = tid;
    float v = -1e30f;
    if (p < P) {
        float dot = 0.f;
#pragma unroll
        for (int n = 0; n < 8; ++n) dot += dotp[(size_t)(b * 8 + n) * P + p];
        v = (dot + Ah[p / WW] + Aw[p % WW]) * (1.f / 1568.f);
    }
    red[tid] = v; __syncthreads();
    for (int s = 128; s > 0; s >>= 1) { if (tid < s) red[tid] = fmaxf(red[tid], red[tid + s]); __syncthreads(); }
    float mx = red[0]; __syncthreads();
    float e = (p < P) ? expf(v - mx) : 0.f;
    red[tid] = e; __syncthreads();
    for (int s = 128; s > 0; s >>= 1) { if (tid < s) red[tid] += red[tid + s]; __syncthreads(); }
    if (p < P) attn_g[b * P + p] = e / red[0];
}

// ---------------- out = concat(x/49, x*attn)
__global__ __launch_bounds__(256) void k_out(const float* __restrict__ x,
                                             const float* __restrict__ attn_g,
                                             float* __restrict__ out) {
    const int total4 = BATCH * CIN * P / 4;
    const int stride = gridDim.x * 256;
    const float4* x4 = (const float4*)x;
    const float4* a4 = (const float4*)attn_g;
    float4* o4 = (float4*)out;
    for (int i4 = blockIdx.x * 256 + threadIdx.x; i4 < total4; i4 += stride) {
        int i = i4 * 4;
        int b = i / (CIN * P);
        int r = i - b * (CIN * P);
        int p0 = r % P;
        float4 xv = x4[i4];
        float4 at = a4[(b * P + p0) >> 2];
        float4 o1 = make_float4(xv.x * (1.f/49.f), xv.y * (1.f/49.f),
                                xv.z * (1.f/49.f), xv.w * (1.f/49.f));
        float4 o2 = make_float4(xv.x * at.x, xv.y * at.y, xv.z * at.z, xv.w * at.w);
        o4[(b * (2 * CIN * P) + r) >> 2] = o1;
        o4[(b * (2 * CIN * P) + CIN * P + r) >> 2] = o2;
    }
}

extern "C" void kernel_launch(void* const* d_in, const int* in_sizes, int n_in,
                              void* d_out, int out_size, void* d_ws, size_t ws_size,
                              hipStream_t stream) {
    const float* x    = (const float*)d_in[0];
    const float* Wq   = (const float*)d_in[1];
    const float* bias = (const float*)d_in[2];
    const float* relw = (const float*)d_in[3];
    const float* relh = (const float*)d_in[4];
    const int*   pair = (const int*)d_in[5];
    float* out = (float*)d_out;
    float* ws  = (float*)d_ws;

    ushort_t* Y16 = (ushort_t*)(ws + OFF_Y16);
    ushort_t* Xb  = (ushort_t*)(ws + OFF_XB);
    ushort_t* Wb  = (ushort_t*)(ws + OFF_WB);
    float* qhp  = ws + OFF_QHP;
    float* qwp  = ws + OFF_QWP;
    float* dotp = ws + OFF_DOTP;
    float* attn = ws + OFF_ATTN;

    k_prep   <<<8192, 256, 0, stream>>>(x, Wq, Xb, Wb);
    k_mfma   <<<784, 256, 0, stream>>>(Xb, Wb, bias, Y16);
    k_normdot<<<BATCH * NHEAD, 256, 0, stream>>>(Y16, pair, qhp, qwp, dotp);
    k_attn2  <<<BATCH, 256, 0, stream>>>(dotp, qhp, qwp, relw, relh, attn);
    k_out    <<<2048, 256, 0, stream>>>(x, attn, out);
}